// Round 1
// baseline (609.868 us; speedup 1.0000x reference)
//
#include <hip/hip_runtime.h>

#define NN 8192
#define DD 768
#define EE 131072
#define BBg 64
#define LLn 128
#define CCh 384

typedef unsigned short u16;
typedef __attribute__((ext_vector_type(8))) short short8;
typedef __attribute__((ext_vector_type(4))) float f32x4;

__device__ __forceinline__ float b2f(u16 u) {
    union { unsigned int i; float f; } x; x.i = ((unsigned int)u) << 16; return x.f;
}
__device__ __forceinline__ u16 f2b(float f) {
    union { float f; unsigned int i; } x; x.f = f;
    unsigned int r = x.i + 0x7fffu + ((x.i >> 16) & 1u);
    return (u16)(r >> 16);
}

// ---------------- CSR build ----------------
__global__ void hist_kernel(const int* __restrict__ dstp, int* __restrict__ counts) {
    int e = blockIdx.x * 256 + threadIdx.x;
    atomicAdd(&counts[dstp[e]], 1);
}

__global__ __launch_bounds__(1024) void scan_kernel(const int* __restrict__ counts,
                                                    int* __restrict__ row_ptr,
                                                    int* __restrict__ cursor) {
    __shared__ int part[1024];
    int t = threadIdx.x;
    int base = t * 8;
    int loc[8]; int s = 0;
#pragma unroll
    for (int i = 0; i < 8; i++) { loc[i] = counts[base + i]; s += loc[i]; }
    part[t] = s;
    __syncthreads();
    for (int off = 1; off < 1024; off <<= 1) {
        int v = (t >= off) ? part[t - off] : 0;
        __syncthreads();
        part[t] += v;
        __syncthreads();
    }
    int run = part[t] - s;  // exclusive chunk offset
#pragma unroll
    for (int i = 0; i < 8; i++) { row_ptr[base + i] = run; cursor[base + i] = run; run += loc[i]; }
    if (t == 1023) row_ptr[NN] = part[1023];
}

__global__ void scatter_kernel(const int* __restrict__ srcp, const int* __restrict__ dstp,
                               int* __restrict__ cursor, int* __restrict__ perm_src,
                               int* __restrict__ perm_dst) {
    int e = blockIdx.x * 256 + threadIdx.x;
    int d = dstp[e];
    int p = atomicAdd(&cursor[d], 1);
    perm_src[p] = srcp[e];
    perm_dst[p] = d;
}

// ---------------- converts ----------------
__global__ void f32_to_bf16_vec(const float* __restrict__ in, u16* __restrict__ out, int n4) {
    int i = blockIdx.x * 256 + threadIdx.x;
    if (i >= n4) return;
    float4 v = ((const float4*)in)[i];
    ushort4 o; o.x = f2b(v.x); o.y = f2b(v.y); o.z = f2b(v.z); o.w = f2b(v.w);
    ((ushort4*)out)[i] = o;
}

// Wt[n*768 + k] = bf16(W[(rowOff+k)*768 + n])
__global__ void transpose_w(const float* __restrict__ W, u16* __restrict__ Wt, int rowOff) {
    int idx = blockIdx.x * 256 + threadIdx.x;
    int n = idx / DD;
    int k = idx - n * DD;
    Wt[idx] = f2b(W[(size_t)(rowOff + k) * DD + n]);
}

__global__ void gather_first(const u16* __restrict__ hb2, u16* __restrict__ hq) {
    int idx = blockIdx.x * 256 + threadIdx.x;  // 64*768
    int b = idx / DD;
    int c = idx - b * DD;
    hq[idx] = hb2[(size_t)(b * LLn) * DD + c];
}

// ---------------- GEMM: C[M,768] = A[M,K](bf16) @ Wt[768,K]^T ----------------
enum { EPI_BF16 = 0, EPI_F32 = 1, EPI_XC = 2 };

__global__ __launch_bounds__(256) void gemm_bf16(const u16* __restrict__ A,
                                                 const u16* __restrict__ Wt,
                                                 const float* __restrict__ bias,
                                                 const float* __restrict__ aq,
                                                 void* __restrict__ outp, int K, int mode) {
    __shared__ u16 As[64][72];   // +8 pad: breaks 128B-stride bank conflicts, keeps 16B align
    __shared__ u16 Bs[64][72];
    const int m0 = blockIdx.y * 64, n0 = blockIdx.x * 64;
    const int t = threadIdx.x;
    const int lane = t & 63, w = t >> 6;
    const int tr = t >> 2, tc = (t & 3) * 16;
    f32x4 acc[4] = {{0,0,0,0},{0,0,0,0},{0,0,0,0},{0,0,0,0}};
    const int fRow = lane & 15;          // A-row / B-col within 16-tile
    const int fK = (lane >> 4) * 8;      // k-offset within 32

    for (int k0 = 0; k0 < K; k0 += 64) {
        int4 a0 = *(const int4*)(A + (size_t)(m0 + tr) * K + k0 + tc);
        int4 a1 = *(const int4*)(A + (size_t)(m0 + tr) * K + k0 + tc + 8);
        int4 b0 = *(const int4*)(Wt + (size_t)(n0 + tr) * K + k0 + tc);
        int4 b1 = *(const int4*)(Wt + (size_t)(n0 + tr) * K + k0 + tc + 8);
        __syncthreads();
        *(int4*)&As[tr][tc] = a0; *(int4*)&As[tr][tc + 8] = a1;
        *(int4*)&Bs[tr][tc] = b0; *(int4*)&Bs[tr][tc + 8] = b1;
        __syncthreads();
#pragma unroll
        for (int s = 0; s < 2; s++) {
            short8 af = *(const short8*)&As[w * 16 + fRow][s * 32 + fK];
#pragma unroll
            for (int g = 0; g < 4; g++) {
                short8 bf = *(const short8*)&Bs[g * 16 + fRow][s * 32 + fK];
                acc[g] = __builtin_amdgcn_mfma_f32_16x16x32_bf16(af, bf, acc[g], 0, 0, 0);
            }
        }
    }
    const int colLocal = lane & 15;
    const int rowLocal = (lane >> 4) * 4;
#pragma unroll
    for (int g = 0; g < 4; g++) {
        int col = n0 + g * 16 + colLocal;
        float bv = bias ? bias[col] : 0.f;
#pragma unroll
        for (int i = 0; i < 4; i++) {
            int row = m0 + w * 16 + rowLocal + i;
            float v = acc[g][i] + bv;
            if (mode == EPI_XC) v = fmaxf(v + aq[(size_t)(row >> 7) * DD + col], 0.f);
            if (mode == EPI_BF16) ((u16*)outp)[(size_t)row * DD + col] = f2b(v);
            else                  ((float*)outp)[(size_t)row * DD + col] = v;
        }
    }
}

// ---------------- edge logits: one wave per CSR slot ----------------
__global__ __launch_bounds__(256) void edge_logits(const u16* __restrict__ qb,
                                                   const u16* __restrict__ kb,
                                                   const int* __restrict__ perm_src,
                                                   const int* __restrict__ perm_dst,
                                                   float* __restrict__ logits) {
    int p = (blockIdx.x * 256 + threadIdx.x) >> 6;
    int lane = threadIdx.x & 63;
    int s = perm_src[p], d = perm_dst[p];
    const u16* qr = qb + (size_t)d * DD + lane * 12;
    const u16* kr = kb + (size_t)s * DD + lane * 12;
    float sum = 0.f;
#pragma unroll
    for (int j = 0; j < 3; j++) {
        ushort4 q4 = *(const ushort4*)(qr + j * 4);
        ushort4 k4 = *(const ushort4*)(kr + j * 4);
        sum += b2f(q4.x) * b2f(k4.x) + b2f(q4.y) * b2f(k4.y)
             + b2f(q4.z) * b2f(k4.z) + b2f(q4.w) * b2f(k4.w);
    }
#pragma unroll
    for (int m = 1; m <= 16; m <<= 1) sum += __shfl_xor(sum, m, 64);
    const float scale = 0.05103103630798288f;  // 1/sqrt(384)
    if (lane == 0)  logits[(size_t)p * 2]     = sum * scale;
    if (lane == 32) logits[(size_t)p * 2 + 1] = sum * scale;
}

// ---------------- per-node softmax + aggregate + skip + relu ----------------
__global__ __launch_bounds__(192) void node_agg(const float* __restrict__ logits,
                                                const u16* __restrict__ vb,
                                                const int* __restrict__ perm_src,
                                                const int* __restrict__ row_ptr,
                                                float* __restrict__ h,
                                                u16* __restrict__ hb_out) {
    int n = blockIdx.x;
    int lo = row_ptr[n], hi = row_ptr[n + 1];
    int deg = hi - lo;
    __shared__ float sms[4];          // m0, m1, inv_s0, inv_s1
    __shared__ float salpha[192][2];
    __shared__ int ssrc[192];
    int t = threadIdx.x, lane = t & 63, w = t >> 6;
    if (w < 2) {  // wave w handles head w
        float mx = -3.4e38f;
        for (int i = lane; i < deg; i += 64) mx = fmaxf(mx, logits[(size_t)(lo + i) * 2 + w]);
#pragma unroll
        for (int m = 1; m <= 32; m <<= 1) mx = fmaxf(mx, __shfl_xor(mx, m, 64));
        float sum = 0.f;
        for (int i = lane; i < deg; i += 64) sum += __expf(logits[(size_t)(lo + i) * 2 + w] - mx);
#pragma unroll
        for (int m = 1; m <= 32; m <<= 1) sum += __shfl_xor(sum, m, 64);
        if (lane == 0) { sms[w] = mx; sms[2 + w] = (deg > 0) ? (1.f / sum) : 0.f; }
    }
    __syncthreads();
    float m0 = sms[0], m1 = sms[1], i0 = sms[2], i1 = sms[3];
    int c = t * 4;
    int hc = (c >= CCh) ? 1 : 0;
    float a0 = 0, a1 = 0, a2 = 0, a3 = 0;
    for (int base = 0; base < deg; base += 192) {
        int i = base + t;
        if (i < deg) {
            ssrc[t] = perm_src[lo + i];
            float l0 = logits[(size_t)(lo + i) * 2];
            float l1 = logits[(size_t)(lo + i) * 2 + 1];
            salpha[t][0] = __expf(l0 - m0) * i0;
            salpha[t][1] = __expf(l1 - m1) * i1;
        }
        __syncthreads();
        int lim = min(192, deg - base);
        for (int j = 0; j < lim; j++) {
            float a = salpha[j][hc];
            ushort4 v4 = *(const ushort4*)(vb + (size_t)ssrc[j] * DD + c);
            a0 += a * b2f(v4.x); a1 += a * b2f(v4.y); a2 += a * b2f(v4.z); a3 += a * b2f(v4.w);
        }
        __syncthreads();
    }
    float4 hv = *(const float4*)(h + (size_t)n * DD + c);
    float r0 = fmaxf(hv.x + a0, 0.f), r1 = fmaxf(hv.y + a1, 0.f);
    float r2 = fmaxf(hv.z + a2, 0.f), r3 = fmaxf(hv.w + a3, 0.f);
    float4 ho; ho.x = r0; ho.y = r1; ho.z = r2; ho.w = r3;
    *(float4*)(h + (size_t)n * DD + c) = ho;
    ushort4 ob; ob.x = f2b(r0); ob.y = f2b(r1); ob.z = f2b(r2); ob.w = f2b(r3);
    *(ushort4*)(hb_out + (size_t)n * DD + c) = ob;
}

// ---------------- score GEMV ----------------
__global__ __launch_bounds__(256) void score_gemv(const float* __restrict__ xc,
                                                  const float* __restrict__ aw,
                                                  const float* __restrict__ ab,
                                                  float* __restrict__ score) {
    int row = (blockIdx.x * 256 + threadIdx.x) >> 6;
    int lane = threadIdx.x & 63;
    const float* xr = xc + (size_t)row * DD + lane * 12;
    const float* wr = aw + lane * 12;
    float s = 0.f;
#pragma unroll
    for (int j = 0; j < 3; j++) {
        float4 x4 = *(const float4*)(xr + j * 4);
        float4 w4 = *(const float4*)(wr + j * 4);
        s += x4.x * w4.x + x4.y * w4.y + x4.z * w4.z + x4.w * w4.w;
    }
#pragma unroll
    for (int m = 1; m <= 32; m <<= 1) s += __shfl_xor(s, m, 64);
    if (lane == 0) score[row] = s + ab[0];
}

// ---------------- per-graph softmax over L + weighted pool ----------------
__global__ __launch_bounds__(192) void pool_kernel(const float* __restrict__ score,
                                                   const float* __restrict__ h,
                                                   float* __restrict__ pooled) {
    int b = blockIdx.x, t = threadIdx.x;
    __shared__ float sprob[LLn];
    if (t < 64) {
        float s0 = score[b * LLn + t];
        float s1 = score[b * LLn + 64 + t];
        float mx = fmaxf(s0, s1);
#pragma unroll
        for (int m = 1; m <= 32; m <<= 1) mx = fmaxf(mx, __shfl_xor(mx, m, 64));
        float e0 = __expf(s0 - mx), e1 = __expf(s1 - mx);
        float sum = e0 + e1;
#pragma unroll
        for (int m = 1; m <= 32; m <<= 1) sum += __shfl_xor(sum, m, 64);
        float inv = 1.f / sum;
        sprob[t] = e0 * inv; sprob[t + 64] = e1 * inv;
    }
    __syncthreads();
    int c = t * 4;
    float a0 = 0, a1 = 0, a2 = 0, a3 = 0;
    for (int l = 0; l < LLn; l++) {
        float wl = sprob[l];
        float4 hv = *(const float4*)(h + (size_t)(b * LLn + l) * DD + c);
        a0 += wl * hv.x; a1 += wl * hv.y; a2 += wl * hv.z; a3 += wl * hv.w;
    }
    float4 o; o.x = a0; o.y = a1; o.z = a2; o.w = a3;
    *(float4*)(pooled + (size_t)b * DD + c) = o;
}

// ---------------- head: fc1+tanh+fc2+log_softmax ----------------
__global__ __launch_bounds__(256) void head_kernel(const float* __restrict__ pooled,
                                                   const float* __restrict__ fc1w,
                                                   const float* __restrict__ fc1b,
                                                   const float* __restrict__ fc2w,
                                                   const float* __restrict__ fc2b,
                                                   float* __restrict__ outp) {
    int b = blockIdx.x, t = threadIdx.x;
    __shared__ float sp[DD];
    __shared__ float su[DD];
    __shared__ float sred[4][3];
    for (int c = t; c < DD; c += 256) sp[c] = pooled[b * DD + c];
    __syncthreads();
    float o0 = fc1b[t * 3 + 0], o1 = fc1b[t * 3 + 1], o2 = fc1b[t * 3 + 2];
    for (int k = 0; k < DD; k++) {
        float pv = sp[k];
        const float* wr = fc1w + (size_t)k * DD + t * 3;
        o0 += pv * wr[0]; o1 += pv * wr[1]; o2 += pv * wr[2];
    }
    su[t * 3 + 0] = tanhf(o0); su[t * 3 + 1] = tanhf(o1); su[t * 3 + 2] = tanhf(o2);
    __syncthreads();
    float p0 = 0, p1 = 0, p2 = 0;
    for (int k = t; k < DD; k += 256) {
        float u = su[k];
        p0 += u * fc2w[k * 3 + 0]; p1 += u * fc2w[k * 3 + 1]; p2 += u * fc2w[k * 3 + 2];
    }
#pragma unroll
    for (int m = 1; m <= 32; m <<= 1) {
        p0 += __shfl_xor(p0, m, 64); p1 += __shfl_xor(p1, m, 64); p2 += __shfl_xor(p2, m, 64);
    }
    int w = t >> 6, lane = t & 63;
    if (lane == 0) { sred[w][0] = p0; sred[w][1] = p1; sred[w][2] = p2; }
    __syncthreads();
    if (t == 0) {
        float z0 = fc2b[0], z1 = fc2b[1], z2 = fc2b[2];
        for (int i = 0; i < 4; i++) { z0 += sred[i][0]; z1 += sred[i][1]; z2 += sred[i][2]; }
        float mx = fmaxf(z0, fmaxf(z1, z2));
        float lse = mx + logf(__expf(z0 - mx) + __expf(z1 - mx) + __expf(z2 - mx));
        outp[b * 3 + 0] = z0 - lse; outp[b * 3 + 1] = z1 - lse; outp[b * 3 + 2] = z2 - lse;
    }
}

// ---------------- launch ----------------
static inline char* carve(char*& p, size_t bytes) {
    char* r = p;
    p += (bytes + 255) & ~(size_t)255;
    return r;
}

extern "C" void kernel_launch(void* const* d_in, const int* in_sizes, int n_in,
                              void* d_out, int out_size, void* d_ws, size_t ws_size,
                              hipStream_t stream) {
    const float* x = (const float*)d_in[0];
    const int* ei = (const int*)d_in[1];
    const int* srcp = ei;
    const int* dstp = ei + EE;
    const float* wL[8] = {(const float*)d_in[2], (const float*)d_in[4], (const float*)d_in[6],
                          (const float*)d_in[8], (const float*)d_in[10], (const float*)d_in[12],
                          (const float*)d_in[14], (const float*)d_in[16]};
    const float* bL[8] = {(const float*)d_in[3], (const float*)d_in[5], (const float*)d_in[7],
                          (const float*)d_in[9], (const float*)d_in[11], (const float*)d_in[13],
                          (const float*)d_in[15], (const float*)d_in[17]};
    const float* atti_w = (const float*)d_in[18];
    const float* atti_b = (const float*)d_in[19];
    const float* atts_w = (const float*)d_in[20];
    const float* atts_b = (const float*)d_in[21];
    const float* fc1_w = (const float*)d_in[22];
    const float* fc1_b = (const float*)d_in[23];
    const float* fc2_w = (const float*)d_in[24];
    const float* fc2_b = (const float*)d_in[25];
    float* outp = (float*)d_out;

    char* p = (char*)d_ws;
    const size_t ndb = (size_t)NN * DD * 2;  // bf16 activation
    const size_t ndf = (size_t)NN * DD * 4;  // fp32 activation
    u16* qb = (u16*)carve(p, ndb);
    u16* kb = (u16*)carve(p, ndb);
    u16* vb = (u16*)carve(p, ndb);
    u16* xb = (u16*)carve(p, ndb);   // layer1 input bf16; reused as layer2 output bf16
    u16* hb = (u16*)carve(p, ndb);   // layer1 output bf16
    float* h = (float*)carve(p, ndf);
    float* xc = (float*)carve(p, ndf);
    u16* wt[10];
    for (int i = 0; i < 10; i++) wt[i] = (u16*)carve(p, (size_t)DD * DD * 2);
    u16* hq = (u16*)carve(p, (size_t)BBg * DD * 2);
    float* Aq = (float*)carve(p, (size_t)BBg * DD * 4);
    float* pooled = (float*)carve(p, (size_t)BBg * DD * 4);
    int* counts = (int*)carve(p, NN * 4);
    int* row_ptr = (int*)carve(p, (NN + 1) * 4);
    int* cursor = (int*)carve(p, NN * 4);
    int* perm_src = (int*)carve(p, EE * 4);
    int* perm_dst = (int*)carve(p, EE * 4);
    float* logits = (float*)carve(p, (size_t)EE * 2 * 4);
    float* score = (float*)carve(p, NN * 4);

    // CSR build
    hipMemsetAsync(counts, 0, NN * 4, stream);
    hist_kernel<<<EE / 256, 256, 0, stream>>>(dstp, counts);
    scan_kernel<<<1, 1024, 0, stream>>>(counts, row_ptr, cursor);
    scatter_kernel<<<EE / 256, 256, 0, stream>>>(srcp, dstp, cursor, perm_src, perm_dst);

    // converts
    f32_to_bf16_vec<<<(NN * DD / 4) / 256, 256, 0, stream>>>(x, xb, NN * DD / 4);
    for (int i = 0; i < 8; i++)
        transpose_w<<<(DD * DD) / 256, 256, 0, stream>>>(wL[i], wt[i], 0);
    transpose_w<<<(DD * DD) / 256, 256, 0, stream>>>(atti_w, wt[8], 0);    // x_q half
    transpose_w<<<(DD * DD) / 256, 256, 0, stream>>>(atti_w, wt[9], DD);   // hp half

    dim3 gg(DD / 64, NN / 64);
    // layer 1
    gemm_bf16<<<gg, 256, 0, stream>>>(xb, wt[0], bL[0], nullptr, qb, DD, EPI_BF16);
    gemm_bf16<<<gg, 256, 0, stream>>>(xb, wt[1], bL[1], nullptr, kb, DD, EPI_BF16);
    gemm_bf16<<<gg, 256, 0, stream>>>(xb, wt[2], bL[2], nullptr, vb, DD, EPI_BF16);
    gemm_bf16<<<gg, 256, 0, stream>>>(xb, wt[3], bL[3], nullptr, h, DD, EPI_F32);
    edge_logits<<<EE / 4, 256, 0, stream>>>(qb, kb, perm_src, perm_dst, logits);
    node_agg<<<NN, 192, 0, stream>>>(logits, vb, perm_src, row_ptr, h, hb);
    // layer 2
    gemm_bf16<<<gg, 256, 0, stream>>>(hb, wt[4], bL[4], nullptr, qb, DD, EPI_BF16);
    gemm_bf16<<<gg, 256, 0, stream>>>(hb, wt[5], bL[5], nullptr, kb, DD, EPI_BF16);
    gemm_bf16<<<gg, 256, 0, stream>>>(hb, wt[6], bL[6], nullptr, vb, DD, EPI_BF16);
    gemm_bf16<<<gg, 256, 0, stream>>>(hb, wt[7], bL[7], nullptr, h, DD, EPI_F32);
    edge_logits<<<EE / 4, 256, 0, stream>>>(qb, kb, perm_src, perm_dst, logits);
    node_agg<<<NN, 192, 0, stream>>>(logits, vb, perm_src, row_ptr, h, xb);  // h=hp, xb=hp_bf16

    // pooling
    gather_first<<<(BBg * DD) / 256, 256, 0, stream>>>(xb, hq);
    gemm_bf16<<<dim3(DD / 64, 1), 256, 0, stream>>>(hq, wt[8], nullptr, nullptr, Aq, DD, EPI_F32);
    gemm_bf16<<<gg, 256, 0, stream>>>(xb, wt[9], atti_b, Aq, xc, DD, EPI_XC);
    score_gemv<<<NN / 4, 256, 0, stream>>>(xc, atts_w, atts_b, score);
    pool_kernel<<<BBg, 192, 0, stream>>>(score, h, pooled);
    head_kernel<<<BBg, 256, 0, stream>>>(pooled, fc1_w, fc1_b, fc2_w, fc2_b, outp);
}

// Round 2
// 515.708 us; speedup vs baseline: 1.1826x; 1.1826x over previous
//
#include <hip/hip_runtime.h>

#define NN 8192
#define DD 768
#define EE 131072
#define BBg 64
#define LLn 128
#define CCh 384

typedef unsigned short u16;
typedef __attribute__((ext_vector_type(8))) short short8;
typedef __attribute__((ext_vector_type(4))) float f32x4;

__device__ __forceinline__ float b2f(u16 u) {
    union { unsigned int i; float f; } x; x.i = ((unsigned int)u) << 16; return x.f;
}
__device__ __forceinline__ u16 f2b(float f) {
    union { float f; unsigned int i; } x; x.f = f;
    unsigned int r = x.i + 0x7fffu + ((x.i >> 16) & 1u);
    return (u16)(r >> 16);
}
__device__ __forceinline__ void gload16(const void* g, void* l) {
    __builtin_amdgcn_global_load_lds((const __attribute__((address_space(1))) void*)g,
                                     (__attribute__((address_space(3))) void*)l, 16, 0, 0);
}

// ---------------- CSR build ----------------
__global__ void hist_kernel(const int* __restrict__ dstp, int* __restrict__ counts) {
    int e = blockIdx.x * 256 + threadIdx.x;
    atomicAdd(&counts[dstp[e]], 1);
}

__global__ __launch_bounds__(1024) void scan_kernel(const int* __restrict__ counts,
                                                    int* __restrict__ row_ptr,
                                                    int* __restrict__ cursor) {
    __shared__ int part[1024];
    int t = threadIdx.x;
    int base = t * 8;
    int loc[8]; int s = 0;
#pragma unroll
    for (int i = 0; i < 8; i++) { loc[i] = counts[base + i]; s += loc[i]; }
    part[t] = s;
    __syncthreads();
    for (int off = 1; off < 1024; off <<= 1) {
        int v = (t >= off) ? part[t - off] : 0;
        __syncthreads();
        part[t] += v;
        __syncthreads();
    }
    int run = part[t] - s;
#pragma unroll
    for (int i = 0; i < 8; i++) { row_ptr[base + i] = run; cursor[base + i] = run; run += loc[i]; }
    if (t == 1023) row_ptr[NN] = part[1023];
}

__global__ void scatter_kernel(const int* __restrict__ srcp, const int* __restrict__ dstp,
                               int* __restrict__ cursor, int* __restrict__ perm_src,
                               int* __restrict__ perm_dst) {
    int e = blockIdx.x * 256 + threadIdx.x;
    int d = dstp[e];
    int p = atomicAdd(&cursor[d], 1);
    perm_src[p] = srcp[e];
    perm_dst[p] = d;
}

// ---------------- converts ----------------
__global__ void f32_to_bf16_vec(const float* __restrict__ in, u16* __restrict__ out, int n4) {
    int i = blockIdx.x * 256 + threadIdx.x;
    if (i >= n4) return;
    float4 v = ((const float4*)in)[i];
    ushort4 o; o.x = f2b(v.x); o.y = f2b(v.y); o.z = f2b(v.z); o.w = f2b(v.w);
    ((ushort4*)out)[i] = o;
}

// Coalesced LDS-tiled transpose: Wt[n*768+k] = bf16(W[(rowOff+k)*768+n])
__global__ __launch_bounds__(256) void transpose_tiled(const float* __restrict__ W,
                                                       u16* __restrict__ Wt, int rowOff) {
    __shared__ float tile[64][65];   // +1 pad: conflict-free transpose read
    int n0 = blockIdx.x * 64, k0 = blockIdx.y * 64;
    int t = threadIdx.x;
    int tc = t & 63, tr = t >> 6;    // 4 rows per pass
#pragma unroll
    for (int i = 0; i < 16; i++)
        tile[tr + i * 4][tc] = W[(size_t)(rowOff + k0 + tr + i * 4) * DD + n0 + tc];
    __syncthreads();
#pragma unroll
    for (int i = 0; i < 16; i++) {
        int row = tr + i * 4;
        Wt[(size_t)(n0 + row) * DD + k0 + tc] = f2b(tile[tc][row]);
    }
}

__global__ void gather_first(const u16* __restrict__ hb2, u16* __restrict__ hq) {
    int idx = blockIdx.x * 256 + threadIdx.x;  // 64*768
    int b = idx / DD;
    int c = idx - b * DD;
    hq[idx] = hb2[(size_t)(b * LLn) * DD + c];
}

// ---------------- small GEMM (64x64 tile), for M=64 cases ----------------
enum { EPI_F32 = 1, EPI_TANH = 3 };

__global__ __launch_bounds__(256) void gemm_bf16(const u16* __restrict__ A,
                                                 const u16* __restrict__ Wt,
                                                 const float* __restrict__ bias,
                                                 void* __restrict__ outp, int K, int mode) {
    __shared__ u16 As[64][72];
    __shared__ u16 Bs[64][72];
    const int m0 = blockIdx.y * 64, n0 = blockIdx.x * 64;
    const int t = threadIdx.x;
    const int lane = t & 63, w = t >> 6;
    const int tr = t >> 2, tc = (t & 3) * 16;
    f32x4 acc[4] = {{0,0,0,0},{0,0,0,0},{0,0,0,0},{0,0,0,0}};
    const int fRow = lane & 15;
    const int fK = (lane >> 4) * 8;

    for (int k0 = 0; k0 < K; k0 += 64) {
        int4 a0 = *(const int4*)(A + (size_t)(m0 + tr) * K + k0 + tc);
        int4 a1 = *(const int4*)(A + (size_t)(m0 + tr) * K + k0 + tc + 8);
        int4 b0 = *(const int4*)(Wt + (size_t)(n0 + tr) * K + k0 + tc);
        int4 b1 = *(const int4*)(Wt + (size_t)(n0 + tr) * K + k0 + tc + 8);
        __syncthreads();
        *(int4*)&As[tr][tc] = a0; *(int4*)&As[tr][tc + 8] = a1;
        *(int4*)&Bs[tr][tc] = b0; *(int4*)&Bs[tr][tc + 8] = b1;
        __syncthreads();
#pragma unroll
        for (int s = 0; s < 2; s++) {
            short8 af = *(const short8*)&As[w * 16 + fRow][s * 32 + fK];
#pragma unroll
            for (int g = 0; g < 4; g++) {
                short8 bf = *(const short8*)&Bs[g * 16 + fRow][s * 32 + fK];
                acc[g] = __builtin_amdgcn_mfma_f32_16x16x32_bf16(af, bf, acc[g], 0, 0, 0);
            }
        }
    }
    const int colLocal = lane & 15;
    const int rowLocal = (lane >> 4) * 4;
#pragma unroll
    for (int g = 0; g < 4; g++) {
        int col = n0 + g * 16 + colLocal;
        float bv = bias ? bias[col] : 0.f;
#pragma unroll
        for (int i = 0; i < 4; i++) {
            int row = m0 + w * 16 + rowLocal + i;
            float v = acc[g][i] + bv;
            if (mode == EPI_TANH) v = tanhf(v);
            ((float*)outp)[(size_t)row * DD + col] = v;
        }
    }
}

// ---------------- big GEMM: m97 structure (128x128 tile, global_load_lds w16) ----------------
enum { MODE_QKVS = 0, MODE_XC = 1 };

__global__ __launch_bounds__(256) void gemm128(const u16* __restrict__ A,
                                               const u16* __restrict__ Wt, int K,
                                               const float* __restrict__ b0,
                                               const float* __restrict__ b1,
                                               const float* __restrict__ b2,
                                               const float* __restrict__ b3,
                                               void* __restrict__ o0, void* __restrict__ o1,
                                               void* __restrict__ o2, void* __restrict__ o3,
                                               const float* __restrict__ aq, int mode) {
    __shared__ u16 As[128 * 64];   // no pad: global_load_lds needs contiguous lane order
    __shared__ u16 Bs[128 * 64];
    const int t = threadIdx.x;
    const int lane = t & 63, w = t >> 6;
    const int wr = w >> 1, wc = w & 1;          // wave quadrant: 64x64
    const int m0 = blockIdx.y * 128, n0 = blockIdx.x * 128;
    const int fRow = lane & 15, fThr = lane >> 4;
    f32x4 acc[4][4] = {};
    const u16* Abase = A + (size_t)m0 * K;
    const u16* Bbase = Wt + (size_t)n0 * K;

    for (int k0 = 0; k0 < K; k0 += 64) {
        __syncthreads();   // previous compute done before LDS overwrite
#pragma unroll
        for (int i = 0; i < 4; i++) {
            int c = t + 256 * i;                // chunk: row=c>>3, 16B col chunk=c&7
            int row = c >> 3, col = (c & 7) * 8;
            gload16(Abase + (size_t)row * K + k0 + col, (char*)As + (size_t)c * 16);
            gload16(Bbase + (size_t)row * K + k0 + col, (char*)Bs + (size_t)c * 16);
        }
        __syncthreads();   // compiler drains vmcnt here
#pragma unroll
        for (int kk = 0; kk < 64; kk += 32) {
            short8 af[4], bf[4];
#pragma unroll
            for (int i = 0; i < 4; i++)
                af[i] = *(const short8*)&As[(wr * 64 + i * 16 + fRow) * 64 + kk + fThr * 8];
#pragma unroll
            for (int g = 0; g < 4; g++)
                bf[g] = *(const short8*)&Bs[(wc * 64 + g * 16 + fRow) * 64 + kk + fThr * 8];
#pragma unroll
            for (int i = 0; i < 4; i++)
#pragma unroll
                for (int g = 0; g < 4; g++)
                    acc[i][g] = __builtin_amdgcn_mfma_f32_16x16x32_bf16(af[i], bf[g], acc[i][g], 0, 0, 0);
        }
    }
    // epilogue: C/D layout col=lane&15, row=(lane>>4)*4+reg
    int chunk = (mode == MODE_QKVS) ? (n0 + wc * 64) / DD : 0;  // 64-col blocks align to 768 boundaries
    const float* bp = (chunk == 0) ? b0 : (chunk == 1) ? b1 : (chunk == 2) ? b2 : b3;
    void* op = (chunk == 0) ? o0 : (chunk == 1) ? o1 : (chunk == 2) ? o2 : o3;
    const int cb = n0 + wc * 64 - chunk * DD;
    const bool asF32 = (mode == MODE_XC) || (chunk == 3);
#pragma unroll
    for (int g = 0; g < 4; g++) {
        int col = cb + g * 16 + fRow;
        float bv = bp ? bp[col] : 0.f;
#pragma unroll
        for (int i = 0; i < 4; i++) {
            int rowb = m0 + wr * 64 + i * 16 + fThr * 4;
#pragma unroll
            for (int rr = 0; rr < 4; rr++) {
                int row = rowb + rr;
                float v = acc[i][g][rr] + bv;
                if (mode == MODE_XC) v = fmaxf(v + aq[(size_t)(row >> 7) * DD + col], 0.f);
                if (asF32) ((float*)op)[(size_t)row * DD + col] = v;
                else       ((u16*)op)[(size_t)row * DD + col] = f2b(v);
            }
        }
    }
}

// ---------------- edge logits: one wave per CSR slot ----------------
__global__ __launch_bounds__(256) void edge_logits(const u16* __restrict__ qb,
                                                   const u16* __restrict__ kb,
                                                   const int* __restrict__ perm_src,
                                                   const int* __restrict__ perm_dst,
                                                   float* __restrict__ logits) {
    int p = (blockIdx.x * 256 + threadIdx.x) >> 6;
    int lane = threadIdx.x & 63;
    int s = perm_src[p], d = perm_dst[p];
    const u16* qr = qb + (size_t)d * DD + lane * 12;
    const u16* kr = kb + (size_t)s * DD + lane * 12;
    float sum = 0.f;
#pragma unroll
    for (int j = 0; j < 3; j++) {
        ushort4 q4 = *(const ushort4*)(qr + j * 4);
        ushort4 k4 = *(const ushort4*)(kr + j * 4);
        sum += b2f(q4.x) * b2f(k4.x) + b2f(q4.y) * b2f(k4.y)
             + b2f(q4.z) * b2f(k4.z) + b2f(q4.w) * b2f(k4.w);
    }
#pragma unroll
    for (int m = 1; m <= 16; m <<= 1) sum += __shfl_xor(sum, m, 64);
    const float scale = 0.05103103630798288f;  // 1/sqrt(384)
    if (lane == 0)  logits[(size_t)p * 2]     = sum * scale;
    if (lane == 32) logits[(size_t)p * 2 + 1] = sum * scale;
}

// ---------------- per-node softmax + aggregate + skip + relu ----------------
__global__ __launch_bounds__(192) void node_agg(const float* __restrict__ logits,
                                                const u16* __restrict__ vb,
                                                const int* __restrict__ perm_src,
                                                const int* __restrict__ row_ptr,
                                                float* __restrict__ h,
                                                u16* __restrict__ hb_out) {
    int n = blockIdx.x;
    int lo = row_ptr[n], hi = row_ptr[n + 1];
    int deg = hi - lo;
    __shared__ float sms[4];
    __shared__ float salpha[192][2];
    __shared__ int ssrc[192];
    int t = threadIdx.x, lane = t & 63, w = t >> 6;
    if (w < 2) {
        float mx = -3.4e38f;
        for (int i = lane; i < deg; i += 64) mx = fmaxf(mx, logits[(size_t)(lo + i) * 2 + w]);
#pragma unroll
        for (int m = 1; m <= 32; m <<= 1) mx = fmaxf(mx, __shfl_xor(mx, m, 64));
        float sum = 0.f;
        for (int i = lane; i < deg; i += 64) sum += __expf(logits[(size_t)(lo + i) * 2 + w] - mx);
#pragma unroll
        for (int m = 1; m <= 32; m <<= 1) sum += __shfl_xor(sum, m, 64);
        if (lane == 0) { sms[w] = mx; sms[2 + w] = (deg > 0) ? (1.f / sum) : 0.f; }
    }
    __syncthreads();
    float m0 = sms[0], m1 = sms[1], i0 = sms[2], i1 = sms[3];
    int c = t * 4;
    int hc = (c >= CCh) ? 1 : 0;
    float a0 = 0, a1 = 0, a2 = 0, a3 = 0;
    for (int base = 0; base < deg; base += 192) {
        int i = base + t;
        if (i < deg) {
            ssrc[t] = perm_src[lo + i];
            float l0 = logits[(size_t)(lo + i) * 2];
            float l1 = logits[(size_t)(lo + i) * 2 + 1];
            salpha[t][0] = __expf(l0 - m0) * i0;
            salpha[t][1] = __expf(l1 - m1) * i1;
        }
        __syncthreads();
        int lim = min(192, deg - base);
        for (int j = 0; j < lim; j++) {
            float a = salpha[j][hc];
            ushort4 v4 = *(const ushort4*)(vb + (size_t)ssrc[j] * DD + c);
            a0 += a * b2f(v4.x); a1 += a * b2f(v4.y); a2 += a * b2f(v4.z); a3 += a * b2f(v4.w);
        }
        __syncthreads();
    }
    float4 hv = *(const float4*)(h + (size_t)n * DD + c);
    float r0 = fmaxf(hv.x + a0, 0.f), r1 = fmaxf(hv.y + a1, 0.f);
    float r2 = fmaxf(hv.z + a2, 0.f), r3 = fmaxf(hv.w + a3, 0.f);
    float4 ho; ho.x = r0; ho.y = r1; ho.z = r2; ho.w = r3;
    *(float4*)(h + (size_t)n * DD + c) = ho;
    ushort4 ob; ob.x = f2b(r0); ob.y = f2b(r1); ob.z = f2b(r2); ob.w = f2b(r3);
    *(ushort4*)(hb_out + (size_t)n * DD + c) = ob;
}

// ---------------- score GEMV ----------------
__global__ __launch_bounds__(256) void score_gemv(const float* __restrict__ xc,
                                                  const float* __restrict__ aw,
                                                  const float* __restrict__ ab,
                                                  float* __restrict__ score) {
    int row = (blockIdx.x * 256 + threadIdx.x) >> 6;
    int lane = threadIdx.x & 63;
    const float* xr = xc + (size_t)row * DD + lane * 12;
    const float* wr = aw + lane * 12;
    float s = 0.f;
#pragma unroll
    for (int j = 0; j < 3; j++) {
        float4 x4 = *(const float4*)(xr + j * 4);
        float4 w4 = *(const float4*)(wr + j * 4);
        s += x4.x * w4.x + x4.y * w4.y + x4.z * w4.z + x4.w * w4.w;
    }
#pragma unroll
    for (int m = 1; m <= 32; m <<= 1) s += __shfl_xor(s, m, 64);
    if (lane == 0) score[row] = s + ab[0];
}

// ---------------- per-graph softmax over L + weighted pool ----------------
__global__ __launch_bounds__(192) void pool_kernel(const float* __restrict__ score,
                                                   const float* __restrict__ h,
                                                   float* __restrict__ pooled) {
    int b = blockIdx.x, t = threadIdx.x;
    __shared__ float sprob[LLn];
    if (t < 64) {
        float s0 = score[b * LLn + t];
        float s1 = score[b * LLn + 64 + t];
        float mx = fmaxf(s0, s1);
#pragma unroll
        for (int m = 1; m <= 32; m <<= 1) mx = fmaxf(mx, __shfl_xor(mx, m, 64));
        float e0 = __expf(s0 - mx), e1 = __expf(s1 - mx);
        float sum = e0 + e1;
#pragma unroll
        for (int m = 1; m <= 32; m <<= 1) sum += __shfl_xor(sum, m, 64);
        float inv = 1.f / sum;
        sprob[t] = e0 * inv; sprob[t + 64] = e1 * inv;
    }
    __syncthreads();
    int c = t * 4;
    float a0 = 0, a1 = 0, a2 = 0, a3 = 0;
    for (int l = 0; l < LLn; l++) {
        float wl = sprob[l];
        float4 hv = *(const float4*)(h + (size_t)(b * LLn + l) * DD + c);
        a0 += wl * hv.x; a1 += wl * hv.y; a2 += wl * hv.z; a3 += wl * hv.w;
    }
    float4 o; o.x = a0; o.y = a1; o.z = a2; o.w = a3;
    *(float4*)(pooled + (size_t)b * DD + c) = o;
}

// ---------------- head tail: fc2 + log_softmax ----------------
__global__ __launch_bounds__(256) void head2_kernel(const float* __restrict__ u,
                                                    const float* __restrict__ fc2w,
                                                    const float* __restrict__ fc2b,
                                                    float* __restrict__ outp) {
    int b = blockIdx.x, t = threadIdx.x;
    __shared__ float sred[4][3];
    float p0 = 0, p1 = 0, p2 = 0;
    for (int k = t; k < DD; k += 256) {
        float uv = u[(size_t)b * DD + k];
        p0 += uv * fc2w[k * 3 + 0]; p1 += uv * fc2w[k * 3 + 1]; p2 += uv * fc2w[k * 3 + 2];
    }
#pragma unroll
    for (int m = 1; m <= 32; m <<= 1) {
        p0 += __shfl_xor(p0, m, 64); p1 += __shfl_xor(p1, m, 64); p2 += __shfl_xor(p2, m, 64);
    }
    int w = t >> 6, lane = t & 63;
    if (lane == 0) { sred[w][0] = p0; sred[w][1] = p1; sred[w][2] = p2; }
    __syncthreads();
    if (t == 0) {
        float z0 = fc2b[0], z1 = fc2b[1], z2 = fc2b[2];
        for (int i = 0; i < 4; i++) { z0 += sred[i][0]; z1 += sred[i][1]; z2 += sred[i][2]; }
        float mx = fmaxf(z0, fmaxf(z1, z2));
        float lse = mx + logf(__expf(z0 - mx) + __expf(z1 - mx) + __expf(z2 - mx));
        outp[b * 3 + 0] = z0 - lse; outp[b * 3 + 1] = z1 - lse; outp[b * 3 + 2] = z2 - lse;
    }
}

// ---------------- launch ----------------
static inline char* carve(char*& p, size_t bytes) {
    char* r = p;
    p += (bytes + 255) & ~(size_t)255;
    return r;
}

extern "C" void kernel_launch(void* const* d_in, const int* in_sizes, int n_in,
                              void* d_out, int out_size, void* d_ws, size_t ws_size,
                              hipStream_t stream) {
    const float* x = (const float*)d_in[0];
    const int* ei = (const int*)d_in[1];
    const int* srcp = ei;
    const int* dstp = ei + EE;
    const float* wL[8] = {(const float*)d_in[2], (const float*)d_in[4], (const float*)d_in[6],
                          (const float*)d_in[8], (const float*)d_in[10], (const float*)d_in[12],
                          (const float*)d_in[14], (const float*)d_in[16]};
    const float* bL[8] = {(const float*)d_in[3], (const float*)d_in[5], (const float*)d_in[7],
                          (const float*)d_in[9], (const float*)d_in[11], (const float*)d_in[13],
                          (const float*)d_in[15], (const float*)d_in[17]};
    const float* atti_w = (const float*)d_in[18];
    const float* atti_b = (const float*)d_in[19];
    const float* atts_w = (const float*)d_in[20];
    const float* atts_b = (const float*)d_in[21];
    const float* fc1_w = (const float*)d_in[22];
    const float* fc1_b = (const float*)d_in[23];
    const float* fc2_w = (const float*)d_in[24];
    const float* fc2_b = (const float*)d_in[25];
    float* outp = (float*)d_out;

    char* p = (char*)d_ws;
    const size_t ndb = (size_t)NN * DD * 2;
    const size_t ndf = (size_t)NN * DD * 4;
    const size_t wsz = (size_t)DD * DD * 2;
    u16* qb = (u16*)carve(p, ndb);
    u16* kb = (u16*)carve(p, ndb);
    u16* vb = (u16*)carve(p, ndb);
    u16* xb = (u16*)carve(p, ndb);   // layer1 input bf16; reused as layer2 output bf16
    u16* hb = (u16*)carve(p, ndb);   // layer1 output bf16
    float* h = (float*)carve(p, ndf);
    float* xc = (float*)carve(p, ndf);
    u16* wtcat1 = (u16*)carve(p, wsz * 4);   // q|k|v|s layer1, [3072][768]
    u16* wtcat2 = (u16*)carve(p, wsz * 4);
    u16* wt8 = (u16*)carve(p, wsz);          // atti_w x_q half
    u16* wt9 = (u16*)carve(p, wsz);          // atti_w hp half
    u16* wtfc1 = (u16*)carve(p, wsz);
    u16* hq = (u16*)carve(p, (size_t)BBg * DD * 2);
    u16* pb = (u16*)carve(p, (size_t)BBg * DD * 2);
    float* Aq = (float*)carve(p, (size_t)BBg * DD * 4);
    float* pooled = (float*)carve(p, (size_t)BBg * DD * 4);
    float* uu = (float*)carve(p, (size_t)BBg * DD * 4);
    int* counts = (int*)carve(p, NN * 4);
    int* row_ptr = (int*)carve(p, (NN + 1) * 4);
    int* cursor = (int*)carve(p, NN * 4);
    int* perm_src = (int*)carve(p, EE * 4);
    int* perm_dst = (int*)carve(p, EE * 4);
    float* logits = (float*)carve(p, (size_t)EE * 2 * 4);
    float* score = (float*)carve(p, NN * 4);

    // CSR build
    hipMemsetAsync(counts, 0, NN * 4, stream);
    hist_kernel<<<EE / 256, 256, 0, stream>>>(dstp, counts);
    scan_kernel<<<1, 1024, 0, stream>>>(counts, row_ptr, cursor);
    scatter_kernel<<<EE / 256, 256, 0, stream>>>(srcp, dstp, cursor, perm_src, perm_dst);

    // converts + weight transposes (coalesced tiled)
    f32_to_bf16_vec<<<(NN * DD / 4) / 256, 256, 0, stream>>>(x, xb, NN * DD / 4);
    dim3 tg(12, 12);
    for (int i = 0; i < 4; i++)
        transpose_tiled<<<tg, 256, 0, stream>>>(wL[i], wtcat1 + (size_t)i * DD * DD, 0);
    for (int i = 0; i < 4; i++)
        transpose_tiled<<<tg, 256, 0, stream>>>(wL[4 + i], wtcat2 + (size_t)i * DD * DD, 0);
    transpose_tiled<<<tg, 256, 0, stream>>>(atti_w, wt8, 0);
    transpose_tiled<<<tg, 256, 0, stream>>>(atti_w, wt9, DD);
    transpose_tiled<<<tg, 256, 0, stream>>>(fc1_w, wtfc1, 0);

    dim3 gf(24, 64);   // fused QKVS: N=3072, M=8192
    // layer 1
    gemm128<<<gf, 256, 0, stream>>>(xb, wtcat1, DD, bL[0], bL[1], bL[2], bL[3],
                                    qb, kb, vb, h, nullptr, MODE_QKVS);
    edge_logits<<<EE / 4, 256, 0, stream>>>(qb, kb, perm_src, perm_dst, logits);
    node_agg<<<NN, 192, 0, stream>>>(logits, vb, perm_src, row_ptr, h, hb);
    // layer 2
    gemm128<<<gf, 256, 0, stream>>>(hb, wtcat2, DD, bL[4], bL[5], bL[6], bL[7],
                                    qb, kb, vb, h, nullptr, MODE_QKVS);
    edge_logits<<<EE / 4, 256, 0, stream>>>(qb, kb, perm_src, perm_dst, logits);
    node_agg<<<NN, 192, 0, stream>>>(logits, vb, perm_src, row_ptr, h, xb);  // h=hp f32, xb=hp bf16

    // pooling
    gather_first<<<(BBg * DD) / 256, 256, 0, stream>>>(xb, hq);
    gemm_bf16<<<dim3(12, 1), 256, 0, stream>>>(hq, wt8, nullptr, Aq, DD, EPI_F32);
    gemm128<<<dim3(6, 64), 256, 0, stream>>>(xb, wt9, DD, atti_b, nullptr, nullptr, nullptr,
                                             xc, nullptr, nullptr, nullptr, Aq, MODE_XC);
    score_gemv<<<NN / 4, 256, 0, stream>>>(xc, atts_w, atts_b, score);
    pool_kernel<<<BBg, 192, 0, stream>>>(score, h, pooled);

    // head: fc1 as MFMA gemm w/ tanh epilogue, then tiny fc2+log_softmax
    f32_to_bf16_vec<<<(BBg * DD / 4 + 255) / 256, 256, 0, stream>>>(pooled, pb, BBg * DD / 4);
    gemm_bf16<<<dim3(12, 1), 256, 0, stream>>>(pb, wtfc1, fc1_b, uu, DD, EPI_TANH);
    head2_kernel<<<BBg, 256, 0, stream>>>(uu, fc2_w, fc2_b, outp);
}

// Round 3
// 425.011 us; speedup vs baseline: 1.4349x; 1.2134x over previous
//
#include <hip/hip_runtime.h>

#define NN 8192
#define DD 768
#define EE 131072
#define BBg 64
#define LLn 128
#define CCh 384

typedef unsigned short u16;
typedef __attribute__((ext_vector_type(8))) short short8;
typedef __attribute__((ext_vector_type(4))) float f32x4;

__device__ __forceinline__ float b2f(u16 u) {
    union { unsigned int i; float f; } x; x.i = ((unsigned int)u) << 16; return x.f;
}
__device__ __forceinline__ u16 f2b(float f) {
    union { float f; unsigned int i; } x; x.f = f;
    unsigned int r = x.i + 0x7fffu + ((x.i >> 16) & 1u);
    return (u16)(r >> 16);
}
__device__ __forceinline__ void gload16(const void* g, void* l) {
    __builtin_amdgcn_global_load_lds((const __attribute__((address_space(1))) void*)g,
                                     (__attribute__((address_space(3))) void*)l, 16, 0, 0);
}

// ---------------- dense count matrix: cnt[g][dst&127][src&127] ----------------
__global__ void cnt_build(const int* __restrict__ srcp, const int* __restrict__ dstp,
                          int* __restrict__ cnt) {
    int e = blockIdx.x * 256 + threadIdx.x;
    int d = dstp[e], s = srcp[e];
    int g = d >> 7;
    atomicAdd(&cnt[(g << 14) + ((d & 127) << 7) + (s & 127)], 1);
}

// ---------------- converts ----------------
__global__ void f32_to_bf16_vec(const float* __restrict__ in, u16* __restrict__ out, int n4) {
    int i = blockIdx.x * 256 + threadIdx.x;
    if (i >= n4) return;
    float4 v = ((const float4*)in)[i];
    ushort4 o; o.x = f2b(v.x); o.y = f2b(v.y); o.z = f2b(v.z); o.w = f2b(v.w);
    ((ushort4*)out)[i] = o;
}

// Batched coalesced LDS-tiled transpose: dst[n*768+k] = bf16(src[(rowOff+k)*768+n])
struct TP { const float* src; u16* dst; int rowOff; };
struct TP11 { TP a[11]; };

__global__ __launch_bounds__(256) void transpose_batched(TP11 args) {
    __shared__ float tile[64][65];
    TP tp = args.a[blockIdx.z];
    int n0 = blockIdx.x * 64, k0 = blockIdx.y * 64;
    int t = threadIdx.x;
    int tc = t & 63, tr = t >> 6;
#pragma unroll
    for (int i = 0; i < 16; i++)
        tile[tr + i * 4][tc] = tp.src[(size_t)(tp.rowOff + k0 + tr + i * 4) * DD + n0 + tc];
    __syncthreads();
#pragma unroll
    for (int i = 0; i < 16; i++) {
        int row = tr + i * 4;
        tp.dst[(size_t)(n0 + row) * DD + k0 + tc] = f2b(tile[tc][row]);
    }
}

__global__ void gather_first(const u16* __restrict__ hb2, u16* __restrict__ hq) {
    int idx = blockIdx.x * 256 + threadIdx.x;  // 64*768
    int b = idx / DD;
    int c = idx - b * DD;
    hq[idx] = hb2[(size_t)(b * LLn) * DD + c];
}

// ---------------- small GEMM (64x64 tile), for M=64 cases ----------------
enum { EPI_F32 = 1, EPI_TANH = 3 };

__global__ __launch_bounds__(256) void gemm_bf16(const u16* __restrict__ A,
                                                 const u16* __restrict__ Wt,
                                                 const float* __restrict__ bias,
                                                 void* __restrict__ outp, int K, int mode) {
    __shared__ u16 As[64][72];
    __shared__ u16 Bs[64][72];
    const int m0 = blockIdx.y * 64, n0 = blockIdx.x * 64;
    const int t = threadIdx.x;
    const int lane = t & 63, w = t >> 6;
    const int tr = t >> 2, tc = (t & 3) * 16;
    f32x4 acc[4] = {{0,0,0,0},{0,0,0,0},{0,0,0,0},{0,0,0,0}};
    const int fRow = lane & 15;
    const int fK = (lane >> 4) * 8;

    for (int k0 = 0; k0 < K; k0 += 64) {
        int4 a0 = *(const int4*)(A + (size_t)(m0 + tr) * K + k0 + tc);
        int4 a1 = *(const int4*)(A + (size_t)(m0 + tr) * K + k0 + tc + 8);
        int4 b0 = *(const int4*)(Wt + (size_t)(n0 + tr) * K + k0 + tc);
        int4 b1 = *(const int4*)(Wt + (size_t)(n0 + tr) * K + k0 + tc + 8);
        __syncthreads();
        *(int4*)&As[tr][tc] = a0; *(int4*)&As[tr][tc + 8] = a1;
        *(int4*)&Bs[tr][tc] = b0; *(int4*)&Bs[tr][tc + 8] = b1;
        __syncthreads();
#pragma unroll
        for (int s = 0; s < 2; s++) {
            short8 af = *(const short8*)&As[w * 16 + fRow][s * 32 + fK];
#pragma unroll
            for (int g = 0; g < 4; g++) {
                short8 bf = *(const short8*)&Bs[g * 16 + fRow][s * 32 + fK];
                acc[g] = __builtin_amdgcn_mfma_f32_16x16x32_bf16(af, bf, acc[g], 0, 0, 0);
            }
        }
    }
    const int colLocal = lane & 15;
    const int rowLocal = (lane >> 4) * 4;
#pragma unroll
    for (int g = 0; g < 4; g++) {
        int col = n0 + g * 16 + colLocal;
        float bv = bias ? bias[col] : 0.f;
#pragma unroll
        for (int i = 0; i < 4; i++) {
            int row = m0 + w * 16 + rowLocal + i;
            float v = acc[g][i] + bv;
            if (mode == EPI_TANH) v = tanhf(v);
            ((float*)outp)[(size_t)row * DD + col] = v;
        }
    }
}

// ---------------- big GEMM: m97 structure + XOR-swizzled LDS ----------------
// swizzle: 16B chunk (row, cj) lives at LDS slot row*8 + (cj ^ (row&7)).
// staging keeps slot == lane order (global_load_lds requirement) by permuting
// the SOURCE column; fragment reads apply the same xor. 2-way aliasing only.
enum { MODE_QKVS = 0, MODE_XC = 1 };

__global__ __launch_bounds__(256) void gemm128(const u16* __restrict__ A,
                                               const u16* __restrict__ Wt, int K,
                                               const float* __restrict__ b0,
                                               const float* __restrict__ b1,
                                               const float* __restrict__ b2,
                                               const float* __restrict__ b3,
                                               void* __restrict__ o0, void* __restrict__ o1,
                                               void* __restrict__ o2, void* __restrict__ o3,
                                               const float* __restrict__ aq, int mode) {
    __shared__ u16 As[128 * 64];
    __shared__ u16 Bs[128 * 64];
    const int t = threadIdx.x;
    const int lane = t & 63, w = t >> 6;
    const int wr = w >> 1, wc = w & 1;
    const int m0 = blockIdx.y * 128, n0 = blockIdx.x * 128;
    const int fRow = lane & 15, fThr = lane >> 4;
    f32x4 acc[4][4] = {};
    const u16* Abase = A + (size_t)m0 * K;
    const u16* Bbase = Wt + (size_t)n0 * K;

    for (int k0 = 0; k0 < K; k0 += 64) {
        __syncthreads();
#pragma unroll
        for (int i = 0; i < 4; i++) {
            int c = t + 256 * i;
            int row = c >> 3;
            int col = (((c & 7) ^ (row & 7))) * 8;   // swizzled source column
            gload16(Abase + (size_t)row * K + k0 + col, (char*)As + (size_t)c * 16);
            gload16(Bbase + (size_t)row * K + k0 + col, (char*)Bs + (size_t)c * 16);
        }
        __syncthreads();
#pragma unroll
        for (int kk = 0; kk < 64; kk += 32) {
            const int cjW = (kk >> 3) + fThr;
            short8 af[4], bf[4];
#pragma unroll
            for (int i = 0; i < 4; i++) {
                int R = wr * 64 + i * 16 + fRow;
                af[i] = *(const short8*)&As[(R * 8 + (cjW ^ (R & 7))) * 8];
            }
#pragma unroll
            for (int g = 0; g < 4; g++) {
                int R = wc * 64 + g * 16 + fRow;
                bf[g] = *(const short8*)&Bs[(R * 8 + (cjW ^ (R & 7))) * 8];
            }
#pragma unroll
            for (int i = 0; i < 4; i++)
#pragma unroll
                for (int g = 0; g < 4; g++)
                    acc[i][g] = __builtin_amdgcn_mfma_f32_16x16x32_bf16(af[i], bf[g], acc[i][g], 0, 0, 0);
        }
    }
    // epilogue: C/D layout col=lane&15, row=(lane>>4)*4+reg
    int chunk = (mode == MODE_QKVS) ? (n0 + wc * 64) / DD : 0;
    const float* bp = (chunk == 0) ? b0 : (chunk == 1) ? b1 : (chunk == 2) ? b2 : b3;
    void* op = (chunk == 0) ? o0 : (chunk == 1) ? o1 : (chunk == 2) ? o2 : o3;
    const int cb = n0 + wc * 64 - chunk * DD;
    if (mode == MODE_QKVS && chunk == 2) {
        // v output written TRANSPOSED: vT[c][node], per-lane contiguous ushort4
        u16* vt = (u16*)op;
#pragma unroll
        for (int g = 0; g < 4; g++) {
            int col = cb + g * 16 + fRow;
            float bv = bp[col];
#pragma unroll
            for (int i = 0; i < 4; i++) {
                int rowb = m0 + wr * 64 + i * 16 + fThr * 4;
                ushort4 st;
                st.x = f2b(acc[i][g][0] + bv);
                st.y = f2b(acc[i][g][1] + bv);
                st.z = f2b(acc[i][g][2] + bv);
                st.w = f2b(acc[i][g][3] + bv);
                *(ushort4*)(vt + (size_t)col * NN + rowb) = st;
            }
        }
    } else {
        const bool asF32 = (mode == MODE_XC) || (chunk == 3);
#pragma unroll
        for (int g = 0; g < 4; g++) {
            int col = cb + g * 16 + fRow;
            float bv = bp ? bp[col] : 0.f;
#pragma unroll
            for (int i = 0; i < 4; i++) {
                int rowb = m0 + wr * 64 + i * 16 + fThr * 4;
#pragma unroll
                for (int rr = 0; rr < 4; rr++) {
                    int row = rowb + rr;
                    float v = acc[i][g][rr] + bv;
                    if (mode == MODE_XC) v = fmaxf(v + aq[(size_t)(row >> 7) * DD + col], 0.f);
                    if (asF32) ((float*)op)[(size_t)row * DD + col] = v;
                    else       ((u16*)op)[(size_t)row * DD + col] = f2b(v);
                }
            }
        }
    }
}

// ---------------- fused dense attention: QK^T -> masked softmax -> PV ----------------
// grid (half=2, head=2, graph=64); block 256. Exact segment-softmax equivalence:
// P[d][s] = cnt*exp(l-m)/sum(cnt*exp(l-m)); empty rows -> 0.
__global__ __launch_bounds__(256) void attn_fused(const u16* __restrict__ qb,
                                                  const u16* __restrict__ kb,
                                                  const u16* __restrict__ vT,
                                                  const int* __restrict__ cnt,
                                                  float* __restrict__ h,
                                                  u16* __restrict__ hb_out) {
    __shared__ u16 As[64][72];      // Q k-tile
    __shared__ u16 Bs[128][72];     // K k-tile
    __shared__ u16 Pl[64][136];     // P row-major (A-operand for PV), padded
    __shared__ u16 Vt[64][136];     // V^T c-chunk [c][src], padded
    const int half = blockIdx.x, hd = blockIdx.y, g = blockIdx.z;
    const int t = threadIdx.x;
    const int lane = t & 63, w = t >> 6;
    const int fRow = lane & 15, fThr = lane >> 4;
    const int dstBase = g * 128 + half * 64;
    const u16* Qb = qb + (size_t)dstBase * DD + hd * CCh;
    const u16* Kb = kb + (size_t)(g * 128) * DD + hd * CCh;

    // ---- QK^T: M=64 (wave strips of 16), N=128, K=384 ----
    f32x4 acc[8] = {};
    const int trA = t >> 2, tcA = (t & 3) * 16;   // A: 64 rows x 64 cols
    const int trB = t >> 1, tcB = (t & 1) * 32;   // B: 128 rows x 64 cols
    for (int k0 = 0; k0 < CCh; k0 += 64) {
        int4 a0 = *(const int4*)(Qb + (size_t)trA * DD + k0 + tcA);
        int4 a1 = *(const int4*)(Qb + (size_t)trA * DD + k0 + tcA + 8);
        int4 b0 = *(const int4*)(Kb + (size_t)trB * DD + k0 + tcB);
        int4 b1 = *(const int4*)(Kb + (size_t)trB * DD + k0 + tcB + 8);
        int4 b2 = *(const int4*)(Kb + (size_t)trB * DD + k0 + tcB + 16);
        int4 b3 = *(const int4*)(Kb + (size_t)trB * DD + k0 + tcB + 24);
        __syncthreads();
        *(int4*)&As[trA][tcA] = a0; *(int4*)&As[trA][tcA + 8] = a1;
        *(int4*)&Bs[trB][tcB] = b0; *(int4*)&Bs[trB][tcB + 8] = b1;
        *(int4*)&Bs[trB][tcB + 16] = b2; *(int4*)&Bs[trB][tcB + 24] = b3;
        __syncthreads();
#pragma unroll
        for (int kk = 0; kk < 64; kk += 32) {
            short8 af = *(const short8*)&As[w * 16 + fRow][kk + fThr * 8];
#pragma unroll
            for (int j = 0; j < 8; j++) {
                short8 bf = *(const short8*)&Bs[j * 16 + fRow][kk + fThr * 8];
                acc[j] = __builtin_amdgcn_mfma_f32_16x16x32_bf16(af, bf, acc[j], 0, 0, 0);
            }
        }
    }

    // ---- masked softmax (wave w owns rows w*16..w*16+15 completely) ----
    const float scale = 0.05103103630798288f;  // 1/sqrt(384)
    const int* cg = cnt + (g << 14);
    const int rbase = half * 64 + w * 16 + fThr * 4;
    float pv[8][4];
#pragma unroll
    for (int i = 0; i < 4; i++) {
        float m = -3.4e38f;
#pragma unroll
        for (int j = 0; j < 8; j++) {
            float c = (float)cg[(rbase + i) * 128 + j * 16 + fRow];
            float s = acc[j][i] * scale;
            pv[j][i] = c;
            if (c > 0.f) m = fmaxf(m, s);
        }
#pragma unroll
        for (int msk = 1; msk <= 8; msk <<= 1) m = fmaxf(m, __shfl_xor(m, msk, 16));
        float sum = 0.f;
#pragma unroll
        for (int j = 0; j < 8; j++) {
            float p = (pv[j][i] > 0.f) ? pv[j][i] * __expf(acc[j][i] * scale - m) : 0.f;
            pv[j][i] = p; sum += p;
        }
#pragma unroll
        for (int msk = 1; msk <= 8; msk <<= 1) sum += __shfl_xor(sum, msk, 16);
        float inv = (sum > 0.f) ? 1.f / sum : 0.f;
#pragma unroll
        for (int j = 0; j < 8; j++)
            Pl[w * 16 + fThr * 4 + i][j * 16 + fRow] = f2b(pv[j][i] * inv);
    }

    // ---- PV: M=64, N=384 (6 chunks of 64), K=128 ----
    for (int cc = 0; cc < 6; cc++) {
        __syncthreads();   // prior Vt readers done
#pragma unroll
        for (int ii = 0; ii < 4; ii++) {
            int q = t + 256 * ii;           // 1024 chunks: row=q>>4 (c), col=(q&15)*8 (src)
            int row = q >> 4, col = (q & 15) * 8;
            *(int4*)&Vt[row][col] =
                *(const int4*)(vT + (size_t)(hd * CCh + cc * 64 + row) * NN + g * 128 + col);
        }
        __syncthreads();
        f32x4 acc2[4] = {};
#pragma unroll
        for (int kk = 0; kk < 128; kk += 32) {
            short8 af = *(const short8*)&Pl[w * 16 + fRow][kk + fThr * 8];
#pragma unroll
            for (int j = 0; j < 4; j++) {
                short8 bf = *(const short8*)&Vt[j * 16 + fRow][kk + fThr * 8];
                acc2[j] = __builtin_amdgcn_mfma_f32_16x16x32_bf16(af, bf, acc2[j], 0, 0, 0);
            }
        }
#pragma unroll
        for (int j = 0; j < 4; j++) {
            int c = hd * CCh + cc * 64 + j * 16 + fRow;
#pragma unroll
            for (int i = 0; i < 4; i++) {
                int row = dstBase + w * 16 + fThr * 4 + i;
                size_t idx = (size_t)row * DD + c;
                float r = fmaxf(acc2[j][i] + h[idx], 0.f);
                h[idx] = r;
                hb_out[idx] = f2b(r);
            }
        }
    }
}

// ---------------- score GEMV ----------------
__global__ __launch_bounds__(256) void score_gemv(const float* __restrict__ xc,
                                                  const float* __restrict__ aw,
                                                  const float* __restrict__ ab,
                                                  float* __restrict__ score) {
    int row = (blockIdx.x * 256 + threadIdx.x) >> 6;
    int lane = threadIdx.x & 63;
    const float* xr = xc + (size_t)row * DD + lane * 12;
    const float* wr = aw + lane * 12;
    float s = 0.f;
#pragma unroll
    for (int j = 0; j < 3; j++) {
        float4 x4 = *(const float4*)(xr + j * 4);
        float4 w4 = *(const float4*)(wr + j * 4);
        s += x4.x * w4.x + x4.y * w4.y + x4.z * w4.z + x4.w * w4.w;
    }
#pragma unroll
    for (int m = 1; m <= 32; m <<= 1) s += __shfl_xor(s, m, 64);
    if (lane == 0) score[row] = s + ab[0];
}

// ---------------- per-graph softmax over L + weighted pool ----------------
__global__ __launch_bounds__(192) void pool_kernel(const float* __restrict__ score,
                                                   const float* __restrict__ h,
                                                   float* __restrict__ pooled) {
    int b = blockIdx.x, t = threadIdx.x;
    __shared__ float sprob[LLn];
    if (t < 64) {
        float s0 = score[b * LLn + t];
        float s1 = score[b * LLn + 64 + t];
        float mx = fmaxf(s0, s1);
#pragma unroll
        for (int m = 1; m <= 32; m <<= 1) mx = fmaxf(mx, __shfl_xor(mx, m, 64));
        float e0 = __expf(s0 - mx), e1 = __expf(s1 - mx);
        float sum = e0 + e1;
#pragma unroll
        for (int m = 1; m <= 32; m <<= 1) sum += __shfl_xor(sum, m, 64);
        float inv = 1.f / sum;
        sprob[t] = e0 * inv; sprob[t + 64] = e1 * inv;
    }
    __syncthreads();
    int c = t * 4;
    float a0 = 0, a1 = 0, a2 = 0, a3 = 0;
    for (int l = 0; l < LLn; l++) {
        float wl = sprob[l];
        float4 hv = *(const float4*)(h + (size_t)(b * LLn + l) * DD + c);
        a0 += wl * hv.x; a1 += wl * hv.y; a2 += wl * hv.z; a3 += wl * hv.w;
    }
    float4 o; o.x = a0; o.y = a1; o.z = a2; o.w = a3;
    *(float4*)(pooled + (size_t)b * DD + c) = o;
}

// ---------------- head tail: fc2 + log_softmax ----------------
__global__ __launch_bounds__(256) void head2_kernel(const float* __restrict__ u,
                                                    const float* __restrict__ fc2w,
                                                    const float* __restrict__ fc2b,
                                                    float* __restrict__ outp) {
    int b = blockIdx.x, t = threadIdx.x;
    __shared__ float sred[4][3];
    float p0 = 0, p1 = 0, p2 = 0;
    for (int k = t; k < DD; k += 256) {
        float uv = u[(size_t)b * DD + k];
        p0 += uv * fc2w[k * 3 + 0]; p1 += uv * fc2w[k * 3 + 1]; p2 += uv * fc2w[k * 3 + 2];
    }
#pragma unroll
    for (int m = 1; m <= 32; m <<= 1) {
        p0 += __shfl_xor(p0, m, 64); p1 += __shfl_xor(p1, m, 64); p2 += __shfl_xor(p2, m, 64);
    }
    int w = t >> 6, lane = t & 63;
    if (lane == 0) { sred[w][0] = p0; sred[w][1] = p1; sred[w][2] = p2; }
    __syncthreads();
    if (t == 0) {
        float z0 = fc2b[0], z1 = fc2b[1], z2 = fc2b[2];
        for (int i = 0; i < 4; i++) { z0 += sred[i][0]; z1 += sred[i][1]; z2 += sred[i][2]; }
        float mx = fmaxf(z0, fmaxf(z1, z2));
        float lse = mx + logf(__expf(z0 - mx) + __expf(z1 - mx) + __expf(z2 - mx));
        outp[b * 3 + 0] = z0 - lse; outp[b * 3 + 1] = z1 - lse; outp[b * 3 + 2] = z2 - lse;
    }
}

// ---------------- launch ----------------
static inline char* carve(char*& p, size_t bytes) {
    char* r = p;
    p += (bytes + 255) & ~(size_t)255;
    return r;
}

extern "C" void kernel_launch(void* const* d_in, const int* in_sizes, int n_in,
                              void* d_out, int out_size, void* d_ws, size_t ws_size,
                              hipStream_t stream) {
    const float* x = (const float*)d_in[0];
    const int* ei = (const int*)d_in[1];
    const int* srcp = ei;
    const int* dstp = ei + EE;
    const float* wL[8] = {(const float*)d_in[2], (const float*)d_in[4], (const float*)d_in[6],
                          (const float*)d_in[8], (const float*)d_in[10], (const float*)d_in[12],
                          (const float*)d_in[14], (const float*)d_in[16]};
    const float* bL[8] = {(const float*)d_in[3], (const float*)d_in[5], (const float*)d_in[7],
                          (const float*)d_in[9], (const float*)d_in[11], (const float*)d_in[13],
                          (const float*)d_in[15], (const float*)d_in[17]};
    const float* atti_w = (const float*)d_in[18];
    const float* atti_b = (const float*)d_in[19];
    const float* atts_w = (const float*)d_in[20];
    const float* atts_b = (const float*)d_in[21];
    const float* fc1_w = (const float*)d_in[22];
    const float* fc1_b = (const float*)d_in[23];
    const float* fc2_w = (const float*)d_in[24];
    const float* fc2_b = (const float*)d_in[25];
    float* outp = (float*)d_out;

    char* p = (char*)d_ws;
    const size_t ndb = (size_t)NN * DD * 2;
    const size_t ndf = (size_t)NN * DD * 4;
    const size_t wsz = (size_t)DD * DD * 2;
    u16* qb = (u16*)carve(p, ndb);
    u16* kb = (u16*)carve(p, ndb);
    u16* vt = (u16*)carve(p, ndb);   // V transposed: [768][8192]
    u16* xb = (u16*)carve(p, ndb);   // layer1 input bf16; reused as layer2 output bf16
    u16* hb = (u16*)carve(p, ndb);   // layer1 output bf16
    float* h = (float*)carve(p, ndf);
    float* xc = (float*)carve(p, ndf);
    u16* wtcat1 = (u16*)carve(p, wsz * 4);   // q|k|v|s layer1, [3072][768]
    u16* wtcat2 = (u16*)carve(p, wsz * 4);
    u16* wt8 = (u16*)carve(p, wsz);          // atti_w x_q half
    u16* wt9 = (u16*)carve(p, wsz);          // atti_w hp half
    u16* wtfc1 = (u16*)carve(p, wsz);
    u16* hq = (u16*)carve(p, (size_t)BBg * DD * 2);
    u16* pb = (u16*)carve(p, (size_t)BBg * DD * 2);
    float* Aq = (float*)carve(p, (size_t)BBg * DD * 4);
    float* pooled = (float*)carve(p, (size_t)BBg * DD * 4);
    float* uu = (float*)carve(p, (size_t)BBg * DD * 4);
    int* cnt = (int*)carve(p, (size_t)BBg * 128 * 128 * 4);   // 4 MB
    float* score = (float*)carve(p, NN * 4);

    // dense count matrix
    hipMemsetAsync(cnt, 0, (size_t)BBg * 128 * 128 * 4, stream);
    cnt_build<<<EE / 256, 256, 0, stream>>>(srcp, dstp, cnt);

    // converts + batched weight transposes
    f32_to_bf16_vec<<<(NN * DD / 4) / 256, 256, 0, stream>>>(x, xb, NN * DD / 4);
    TP11 tps;
    for (int i = 0; i < 4; i++) tps.a[i] = {wL[i], wtcat1 + (size_t)i * DD * DD, 0};
    for (int i = 0; i < 4; i++) tps.a[4 + i] = {wL[4 + i], wtcat2 + (size_t)i * DD * DD, 0};
    tps.a[8] = {atti_w, wt8, 0};
    tps.a[9] = {atti_w, wt9, DD};
    tps.a[10] = {fc1_w, wtfc1, 0};
    transpose_batched<<<dim3(12, 12, 11), 256, 0, stream>>>(tps);

    dim3 gf(24, 64);           // fused QKVS: N=3072, M=8192
    dim3 ga(2, 2, BBg);        // attention: (dst-half, head, graph)
    // layer 1
    gemm128<<<gf, 256, 0, stream>>>(xb, wtcat1, DD, bL[0], bL[1], bL[2], bL[3],
                                    qb, kb, vt, h, nullptr, MODE_QKVS);
    attn_fused<<<ga, 256, 0, stream>>>(qb, kb, vt, cnt, h, hb);
    // layer 2
    gemm128<<<gf, 256, 0, stream>>>(hb, wtcat2, DD, bL[4], bL[5], bL[6], bL[7],
                                    qb, kb, vt, h, nullptr, MODE_QKVS);
    attn_fused<<<ga, 256, 0, stream>>>(qb, kb, vt, cnt, h, xb);   // h=hp f32, xb=hp bf16

    // pooling
    gather_first<<<(BBg * DD) / 256, 256, 0, stream>>>(xb, hq);
    gemm_bf16<<<dim3(12, 1), 256, 0, stream>>>(hq, wt8, nullptr, Aq, DD, EPI_F32);
    gemm128<<<dim3(6, 64), 256, 0, stream>>>(xb, wt9, DD, atti_b, nullptr, nullptr, nullptr,
                                             xc, nullptr, nullptr, nullptr, Aq, MODE_XC);
    score_gemv<<<NN / 4, 256, 0, stream>>>(xc, atts_w, atts_b, score);
    pool_kernel<<<BBg, 192, 0, stream>>>(score, h, pooled);

    // head: fc1 as MFMA gemm w/ tanh epilogue, then tiny fc2+log_softmax
    f32_to_bf16_vec<<<(BBg * DD / 4 + 255) / 256, 256, 0, stream>>>(pooled, pb, BBg * DD / 4);
    gemm_bf16<<<dim3(12, 1), 256, 0, stream>>>(pb, wtfc1, fc1_b, uu, DD, EPI_TANH);
    head2_kernel<<<BBg, 256, 0, stream>>>(uu, fc2_w, fc2_b, outp);
}

// Round 4
// 359.657 us; speedup vs baseline: 1.6957x; 1.1817x over previous
//
#include <hip/hip_runtime.h>

#define NN 8192
#define DD 768
#define EE 131072
#define BBg 64
#define LLn 128
#define CCh 384

typedef unsigned short u16;
typedef unsigned char u8;
typedef __attribute__((ext_vector_type(8))) short short8;
typedef __attribute__((ext_vector_type(4))) float f32x4;

__device__ __forceinline__ float b2f(u16 u) {
    union { unsigned int i; float f; } x; x.i = ((unsigned int)u) << 16; return x.f;
}
__device__ __forceinline__ u16 f2b(float f) {
    union { float f; unsigned int i; } x; x.f = f;
    unsigned int r = x.i + 0x7fffu + ((x.i >> 16) & 1u);
    return (u16)(r >> 16);
}
__device__ __forceinline__ void gload16(const void* g, void* l) {
    __builtin_amdgcn_global_load_lds((const __attribute__((address_space(1))) void*)g,
                                     (__attribute__((address_space(3))) void*)l, 16, 0, 0);
}

// ---------------- dense count matrix, packed u8: cnt[g][dst&127][src&127] ----------------
__global__ void cnt_build(const int* __restrict__ srcp, const int* __restrict__ dstp,
                          unsigned int* __restrict__ cnt32) {
    int e = blockIdx.x * 256 + threadIdx.x;
    int d = dstp[e], s = srcp[e];
    int g = d >> 7;
    int idx = (g << 14) + ((d & 127) << 7) + (s & 127);
    atomicAdd(&cnt32[idx >> 2], 1u << ((idx & 3) * 8));
}

// ---------------- converts ----------------
__global__ void f32_to_bf16_vec(const float* __restrict__ in, u16* __restrict__ out, int n4) {
    int i = blockIdx.x * 256 + threadIdx.x;
    if (i >= n4) return;
    float4 v = ((const float4*)in)[i];
    ushort4 o; o.x = f2b(v.x); o.y = f2b(v.y); o.z = f2b(v.z); o.w = f2b(v.w);
    ((ushort4*)out)[i] = o;
}

// Batched coalesced LDS-tiled transpose: dst[n*768+k] = bf16(src[(rowOff+k)*768+n])
struct TP { const float* src; u16* dst; int rowOff; };
struct TP11 { TP a[11]; };

__global__ __launch_bounds__(256) void transpose_batched(TP11 args) {
    __shared__ float tile[64][65];
    TP tp = args.a[blockIdx.z];
    int n0 = blockIdx.x * 64, k0 = blockIdx.y * 64;
    int t = threadIdx.x;
    int tc = t & 63, tr = t >> 6;
#pragma unroll
    for (int i = 0; i < 16; i++)
        tile[tr + i * 4][tc] = tp.src[(size_t)(tp.rowOff + k0 + tr + i * 4) * DD + n0 + tc];
    __syncthreads();
#pragma unroll
    for (int i = 0; i < 16; i++) {
        int row = tr + i * 4;
        tp.dst[(size_t)(n0 + row) * DD + k0 + tc] = f2b(tile[tc][row]);
    }
}

__global__ void gather_first(const u16* __restrict__ hb2, u16* __restrict__ hq) {
    int idx = blockIdx.x * 256 + threadIdx.x;  // 64*768
    int b = idx / DD;
    int c = idx - b * DD;
    hq[idx] = hb2[(size_t)(b * LLn) * DD + c];
}

// ---------------- small GEMM (64x64 tile), for M=64 cases ----------------
enum { EPI_F32 = 1, EPI_TANH = 3 };

__global__ __launch_bounds__(256) void gemm_bf16(const u16* __restrict__ A,
                                                 const u16* __restrict__ Wt,
                                                 const float* __restrict__ bias,
                                                 void* __restrict__ outp, int K, int mode) {
    __shared__ u16 As[64][72];
    __shared__ u16 Bs[64][72];
    const int m0 = blockIdx.y * 64, n0 = blockIdx.x * 64;
    const int t = threadIdx.x;
    const int lane = t & 63, w = t >> 6;
    const int tr = t >> 2, tc = (t & 3) * 16;
    f32x4 acc[4] = {{0,0,0,0},{0,0,0,0},{0,0,0,0},{0,0,0,0}};
    const int fRow = lane & 15;
    const int fK = (lane >> 4) * 8;

    for (int k0 = 0; k0 < K; k0 += 64) {
        int4 a0 = *(const int4*)(A + (size_t)(m0 + tr) * K + k0 + tc);
        int4 a1 = *(const int4*)(A + (size_t)(m0 + tr) * K + k0 + tc + 8);
        int4 b0 = *(const int4*)(Wt + (size_t)(n0 + tr) * K + k0 + tc);
        int4 b1 = *(const int4*)(Wt + (size_t)(n0 + tr) * K + k0 + tc + 8);
        __syncthreads();
        *(int4*)&As[tr][tc] = a0; *(int4*)&As[tr][tc + 8] = a1;
        *(int4*)&Bs[tr][tc] = b0; *(int4*)&Bs[tr][tc + 8] = b1;
        __syncthreads();
#pragma unroll
        for (int s = 0; s < 2; s++) {
            short8 af = *(const short8*)&As[w * 16 + fRow][s * 32 + fK];
#pragma unroll
            for (int g = 0; g < 4; g++) {
                short8 bf = *(const short8*)&Bs[g * 16 + fRow][s * 32 + fK];
                acc[g] = __builtin_amdgcn_mfma_f32_16x16x32_bf16(af, bf, acc[g], 0, 0, 0);
            }
        }
    }
    const int colLocal = lane & 15;
    const int rowLocal = (lane >> 4) * 4;
#pragma unroll
    for (int g = 0; g < 4; g++) {
        int col = n0 + g * 16 + colLocal;
        float bv = bias ? bias[col] : 0.f;
#pragma unroll
        for (int i = 0; i < 4; i++) {
            int row = m0 + w * 16 + rowLocal + i;
            float v = acc[g][i] + bv;
            if (mode == EPI_TANH) v = tanhf(v);
            ((float*)outp)[(size_t)row * DD + col] = v;
        }
    }
}

// ---------------- big GEMM: m97 structure + XOR-swizzled LDS ----------------
// swizzle: 16B chunk (row, cj) lives at LDS slot row*8 + (cj ^ (row&7)).
enum { MODE_QKVS = 0, MODE_XC = 1 };

__global__ __launch_bounds__(256) void gemm128(const u16* __restrict__ A,
                                               const u16* __restrict__ Wt, int K,
                                               const float* __restrict__ b0,
                                               const float* __restrict__ b1,
                                               const float* __restrict__ b2,
                                               const float* __restrict__ b3,
                                               void* __restrict__ o0, void* __restrict__ o1,
                                               void* __restrict__ o2, void* __restrict__ o3,
                                               const float* __restrict__ aq, int mode) {
    __shared__ u16 As[128 * 64];
    __shared__ u16 Bs[128 * 64];
    const int t = threadIdx.x;
    const int lane = t & 63, w = t >> 6;
    const int wr = w >> 1, wc = w & 1;
    const int m0 = blockIdx.y * 128, n0 = blockIdx.x * 128;
    const int fRow = lane & 15, fThr = lane >> 4;
    f32x4 acc[4][4] = {};
    const u16* Abase = A + (size_t)m0 * K;
    const u16* Bbase = Wt + (size_t)n0 * K;

    for (int k0 = 0; k0 < K; k0 += 64) {
        __syncthreads();
#pragma unroll
        for (int i = 0; i < 4; i++) {
            int c = t + 256 * i;
            int row = c >> 3;
            int col = (((c & 7) ^ (row & 7))) * 8;   // swizzled source column
            gload16(Abase + (size_t)row * K + k0 + col, (char*)As + (size_t)c * 16);
            gload16(Bbase + (size_t)row * K + k0 + col, (char*)Bs + (size_t)c * 16);
        }
        __syncthreads();
#pragma unroll
        for (int kk = 0; kk < 64; kk += 32) {
            const int cjW = (kk >> 3) + fThr;
            short8 af[4], bf[4];
#pragma unroll
            for (int i = 0; i < 4; i++) {
                int R = wr * 64 + i * 16 + fRow;
                af[i] = *(const short8*)&As[(R * 8 + (cjW ^ (R & 7))) * 8];
            }
#pragma unroll
            for (int g = 0; g < 4; g++) {
                int R = wc * 64 + g * 16 + fRow;
                bf[g] = *(const short8*)&Bs[(R * 8 + (cjW ^ (R & 7))) * 8];
            }
#pragma unroll
            for (int i = 0; i < 4; i++)
#pragma unroll
                for (int g = 0; g < 4; g++)
                    acc[i][g] = __builtin_amdgcn_mfma_f32_16x16x32_bf16(af[i], bf[g], acc[i][g], 0, 0, 0);
        }
    }
    // epilogue: C/D layout col=lane&15, row=(lane>>4)*4+reg
    if (mode == MODE_XC) {
        // relu(acc + atti_b + Aq) dotted with atts_w, reduced to score[row] (never materialized)
        float* scoreOut = (float*)o0;
        const float* aw = b1;          // atts_w
        const int cb2 = n0 + wc * 64;
        float rsum[4][4] = {};
#pragma unroll
        for (int g = 0; g < 4; g++) {
            int col = cb2 + g * 16 + fRow;
            float bv = b0[col], av = aw[col];
#pragma unroll
            for (int i = 0; i < 4; i++) {
                int rowb = m0 + wr * 64 + i * 16 + fThr * 4;
#pragma unroll
                for (int rr = 0; rr < 4; rr++) {
                    int row = rowb + rr;
                    float v = fmaxf(acc[i][g][rr] + bv + aq[(size_t)(row >> 7) * DD + col], 0.f);
                    rsum[i][rr] += v * av;
                }
            }
        }
#pragma unroll
        for (int i = 0; i < 4; i++)
#pragma unroll
            for (int rr = 0; rr < 4; rr++) {
                float s = rsum[i][rr];
                s += __shfl_xor(s, 1, 16); s += __shfl_xor(s, 2, 16);
                s += __shfl_xor(s, 4, 16); s += __shfl_xor(s, 8, 16);
                if (fRow == 0)
                    atomicAdd(&scoreOut[m0 + wr * 64 + i * 16 + fThr * 4 + rr], s);
            }
        return;
    }
    int chunk = (n0 + wc * 64) / DD;
    const float* bp = (chunk == 0) ? b0 : (chunk == 1) ? b1 : (chunk == 2) ? b2 : b3;
    void* op = (chunk == 0) ? o0 : (chunk == 1) ? o1 : (chunk == 2) ? o2 : o3;
    const int cb = n0 + wc * 64 - chunk * DD;
    if (chunk == 2) {
        // v output written TRANSPOSED: vT[c][node], per-lane contiguous ushort4
        u16* vt = (u16*)op;
#pragma unroll
        for (int g = 0; g < 4; g++) {
            int col = cb + g * 16 + fRow;
            float bv = bp[col];
#pragma unroll
            for (int i = 0; i < 4; i++) {
                int rowb = m0 + wr * 64 + i * 16 + fThr * 4;
                ushort4 st;
                st.x = f2b(acc[i][g][0] + bv);
                st.y = f2b(acc[i][g][1] + bv);
                st.z = f2b(acc[i][g][2] + bv);
                st.w = f2b(acc[i][g][3] + bv);
                *(ushort4*)(vt + (size_t)col * NN + rowb) = st;
            }
        }
    } else {
#pragma unroll
        for (int g = 0; g < 4; g++) {
            int col = cb + g * 16 + fRow;
            float bv = bp[col];
#pragma unroll
            for (int i = 0; i < 4; i++) {
                int rowb = m0 + wr * 64 + i * 16 + fThr * 4;
#pragma unroll
                for (int rr = 0; rr < 4; rr++) {
                    int row = rowb + rr;
                    ((u16*)op)[(size_t)row * DD + col] = f2b(acc[i][g][rr] + bv);
                }
            }
        }
    }
}

// ---------------- fused dense attention: QK^T -> masked softmax -> PV ----------------
// grid (half=2, head=2, graph=64); block 256. skip (hs) bf16 in, out bf16 only.
__global__ __launch_bounds__(256) void attn_fused(const u16* __restrict__ qb,
                                                  const u16* __restrict__ kb,
                                                  const u16* __restrict__ vT,
                                                  const u8* __restrict__ cnt,
                                                  const u16* __restrict__ hs,
                                                  u16* __restrict__ out) {
    __shared__ u16 As[64][72];      // Q k-tile
    __shared__ u16 Bs[128][72];     // K k-tile
    __shared__ u16 Pl[64][136];     // P row-major (A-operand for PV), padded
    __shared__ u16 Vt[64][136];     // V^T c-chunk [c][src], padded
    const int half = blockIdx.x, hd = blockIdx.y, g = blockIdx.z;
    const int t = threadIdx.x;
    const int lane = t & 63, w = t >> 6;
    const int fRow = lane & 15, fThr = lane >> 4;
    const int dstBase = g * 128 + half * 64;
    const u16* Qb = qb + (size_t)dstBase * DD + hd * CCh;
    const u16* Kb = kb + (size_t)(g * 128) * DD + hd * CCh;

    // ---- QK^T: M=64 (wave strips of 16), N=128, K=384 ----
    f32x4 acc[8] = {};
    const int trA = t >> 2, tcA = (t & 3) * 16;
    const int trB = t >> 1, tcB = (t & 1) * 32;
    for (int k0 = 0; k0 < CCh; k0 += 64) {
        int4 a0 = *(const int4*)(Qb + (size_t)trA * DD + k0 + tcA);
        int4 a1 = *(const int4*)(Qb + (size_t)trA * DD + k0 + tcA + 8);
        int4 b0 = *(const int4*)(Kb + (size_t)trB * DD + k0 + tcB);
        int4 b1 = *(const int4*)(Kb + (size_t)trB * DD + k0 + tcB + 8);
        int4 b2 = *(const int4*)(Kb + (size_t)trB * DD + k0 + tcB + 16);
        int4 b3 = *(const int4*)(Kb + (size_t)trB * DD + k0 + tcB + 24);
        __syncthreads();
        *(int4*)&As[trA][tcA] = a0; *(int4*)&As[trA][tcA + 8] = a1;
        *(int4*)&Bs[trB][tcB] = b0; *(int4*)&Bs[trB][tcB + 8] = b1;
        *(int4*)&Bs[trB][tcB + 16] = b2; *(int4*)&Bs[trB][tcB + 24] = b3;
        __syncthreads();
#pragma unroll
        for (int kk = 0; kk < 64; kk += 32) {
            short8 af = *(const short8*)&As[w * 16 + fRow][kk + fThr * 8];
#pragma unroll
            for (int j = 0; j < 8; j++) {
                short8 bf = *(const short8*)&Bs[j * 16 + fRow][kk + fThr * 8];
                acc[j] = __builtin_amdgcn_mfma_f32_16x16x32_bf16(af, bf, acc[j], 0, 0, 0);
            }
        }
    }

    // ---- masked softmax (wave w owns rows w*16..w*16+15 completely) ----
    const float scale = 0.05103103630798288f;  // 1/sqrt(384)
    const u8* cg = cnt + ((size_t)g << 14);
    const int rbase = half * 64 + w * 16 + fThr * 4;
    float pv[8][4];
#pragma unroll
    for (int i = 0; i < 4; i++) {
        float m = -3.4e38f;
#pragma unroll
        for (int j = 0; j < 8; j++) {
            float c = (float)cg[(rbase + i) * 128 + j * 16 + fRow];
            float s = acc[j][i] * scale;
            pv[j][i] = c;
            if (c > 0.f) m = fmaxf(m, s);
        }
#pragma unroll
        for (int msk = 1; msk <= 8; msk <<= 1) m = fmaxf(m, __shfl_xor(m, msk, 16));
        float sum = 0.f;
#pragma unroll
        for (int j = 0; j < 8; j++) {
            float p = (pv[j][i] > 0.f) ? pv[j][i] * __expf(acc[j][i] * scale - m) : 0.f;
            pv[j][i] = p; sum += p;
        }
#pragma unroll
        for (int msk = 1; msk <= 8; msk <<= 1) sum += __shfl_xor(sum, msk, 16);
        float inv = (sum > 0.f) ? 1.f / sum : 0.f;
#pragma unroll
        for (int j = 0; j < 8; j++)
            Pl[w * 16 + fThr * 4 + i][j * 16 + fRow] = f2b(pv[j][i] * inv);
    }

    // ---- PV: M=64, N=384 (6 chunks of 64), K=128 ----
    for (int cc = 0; cc < 6; cc++) {
        __syncthreads();
#pragma unroll
        for (int ii = 0; ii < 4; ii++) {
            int q = t + 256 * ii;
            int row = q >> 4, col = (q & 15) * 8;
            *(int4*)&Vt[row][col] =
                *(const int4*)(vT + (size_t)(hd * CCh + cc * 64 + row) * NN + g * 128 + col);
        }
        __syncthreads();
        f32x4 acc2[4] = {};
#pragma unroll
        for (int kk = 0; kk < 128; kk += 32) {
            short8 af = *(const short8*)&Pl[w * 16 + fRow][kk + fThr * 8];
#pragma unroll
            for (int j = 0; j < 4; j++) {
                short8 bf = *(const short8*)&Vt[j * 16 + fRow][kk + fThr * 8];
                acc2[j] = __builtin_amdgcn_mfma_f32_16x16x32_bf16(af, bf, acc2[j], 0, 0, 0);
            }
        }
#pragma unroll
        for (int j = 0; j < 4; j++) {
            int c = hd * CCh + cc * 64 + j * 16 + fRow;
#pragma unroll
            for (int i = 0; i < 4; i++) {
                int row = dstBase + w * 16 + fThr * 4 + i;
                size_t idx = (size_t)row * DD + c;
                float r = fmaxf(acc2[j][i] + b2f(hs[idx]), 0.f);
                out[idx] = f2b(r);
            }
        }
    }
}

// ---------------- per-graph softmax over L + weighted pool (bf16 h) ----------------
__global__ __launch_bounds__(192) void pool_kernel(const float* __restrict__ score,
                                                   const u16* __restrict__ hx,
                                                   float* __restrict__ pooled) {
    int b = blockIdx.x, t = threadIdx.x;
    __shared__ float sprob[LLn];
    if (t < 64) {
        float s0 = score[b * LLn + t];
        float s1 = score[b * LLn + 64 + t];
        float mx = fmaxf(s0, s1);
#pragma unroll
        for (int m = 1; m <= 32; m <<= 1) mx = fmaxf(mx, __shfl_xor(mx, m, 64));
        float e0 = __expf(s0 - mx), e1 = __expf(s1 - mx);
        float sum = e0 + e1;
#pragma unroll
        for (int m = 1; m <= 32; m <<= 1) sum += __shfl_xor(sum, m, 64);
        float inv = 1.f / sum;
        sprob[t] = e0 * inv; sprob[t + 64] = e1 * inv;
    }
    __syncthreads();
    int c = t * 4;
    float a0 = 0, a1 = 0, a2 = 0, a3 = 0;
    for (int l = 0; l < LLn; l++) {
        float wl = sprob[l];
        ushort4 hv = *(const ushort4*)(hx + (size_t)(b * LLn + l) * DD + c);
        a0 += wl * b2f(hv.x); a1 += wl * b2f(hv.y); a2 += wl * b2f(hv.z); a3 += wl * b2f(hv.w);
    }
    float4 o; o.x = a0; o.y = a1; o.z = a2; o.w = a3;
    *(float4*)(pooled + (size_t)b * DD + c) = o;
}

// ---------------- head tail: fc2 + log_softmax ----------------
__global__ __launch_bounds__(256) void head2_kernel(const float* __restrict__ u,
                                                    const float* __restrict__ fc2w,
                                                    const float* __restrict__ fc2b,
                                                    float* __restrict__ outp) {
    int b = blockIdx.x, t = threadIdx.x;
    __shared__ float sred[4][3];
    float p0 = 0, p1 = 0, p2 = 0;
    for (int k = t; k < DD; k += 256) {
        float uv = u[(size_t)b * DD + k];
        p0 += uv * fc2w[k * 3 + 0]; p1 += uv * fc2w[k * 3 + 1]; p2 += uv * fc2w[k * 3 + 2];
    }
#pragma unroll
    for (int m = 1; m <= 32; m <<= 1) {
        p0 += __shfl_xor(p0, m, 64); p1 += __shfl_xor(p1, m, 64); p2 += __shfl_xor(p2, m, 64);
    }
    int w = t >> 6, lane = t & 63;
    if (lane == 0) { sred[w][0] = p0; sred[w][1] = p1; sred[w][2] = p2; }
    __syncthreads();
    if (t == 0) {
        float z0 = fc2b[0], z1 = fc2b[1], z2 = fc2b[2];
        for (int i = 0; i < 4; i++) { z0 += sred[i][0]; z1 += sred[i][1]; z2 += sred[i][2]; }
        float mx = fmaxf(z0, fmaxf(z1, z2));
        float lse = mx + logf(__expf(z0 - mx) + __expf(z1 - mx) + __expf(z2 - mx));
        outp[b * 3 + 0] = z0 - lse; outp[b * 3 + 1] = z1 - lse; outp[b * 3 + 2] = z2 - lse;
    }
}

// ---------------- launch ----------------
static inline char* carve(char*& p, size_t bytes) {
    char* r = p;
    p += (bytes + 255) & ~(size_t)255;
    return r;
}

extern "C" void kernel_launch(void* const* d_in, const int* in_sizes, int n_in,
                              void* d_out, int out_size, void* d_ws, size_t ws_size,
                              hipStream_t stream) {
    const float* x = (const float*)d_in[0];
    const int* ei = (const int*)d_in[1];
    const int* srcp = ei;
    const int* dstp = ei + EE;
    const float* wL[8] = {(const float*)d_in[2], (const float*)d_in[4], (const float*)d_in[6],
                          (const float*)d_in[8], (const float*)d_in[10], (const float*)d_in[12],
                          (const float*)d_in[14], (const float*)d_in[16]};
    const float* bL[8] = {(const float*)d_in[3], (const float*)d_in[5], (const float*)d_in[7],
                          (const float*)d_in[9], (const float*)d_in[11], (const float*)d_in[13],
                          (const float*)d_in[15], (const float*)d_in[17]};
    const float* atti_w = (const float*)d_in[18];
    const float* atti_b = (const float*)d_in[19];
    const float* atts_w = (const float*)d_in[20];
    const float* fc1_w = (const float*)d_in[22];
    const float* fc1_b = (const float*)d_in[23];
    const float* fc2_w = (const float*)d_in[24];
    const float* fc2_b = (const float*)d_in[25];
    float* outp = (float*)d_out;

    char* p = (char*)d_ws;
    const size_t ndb = (size_t)NN * DD * 2;
    const size_t wsz = (size_t)DD * DD * 2;
    u16* qb = (u16*)carve(p, ndb);
    u16* kb = (u16*)carve(p, ndb);
    u16* vt = (u16*)carve(p, ndb);   // V transposed: [768][8192]
    u16* xb = (u16*)carve(p, ndb);   // layer1 input bf16; reused as layer2 attn output
    u16* hb = (u16*)carve(p, ndb);   // layer1 attn output bf16
    u16* hs = (u16*)carve(p, ndb);   // skip (x@ws+bs) bf16
    u16* wtcat1 = (u16*)carve(p, wsz * 4);   // q|k|v|s layer1, [3072][768]
    u16* wtcat2 = (u16*)carve(p, wsz * 4);
    u16* wt8 = (u16*)carve(p, wsz);          // atti_w x_q half
    u16* wt9 = (u16*)carve(p, wsz);          // atti_w hp half
    u16* wtfc1 = (u16*)carve(p, wsz);
    u16* hq = (u16*)carve(p, (size_t)BBg * DD * 2);
    u16* pb = (u16*)carve(p, (size_t)BBg * DD * 2);
    float* Aq = (float*)carve(p, (size_t)BBg * DD * 4);
    float* pooled = (float*)carve(p, (size_t)BBg * DD * 4);
    float* uu = (float*)carve(p, (size_t)BBg * DD * 4);
    u8* cnt = (u8*)carve(p, (size_t)BBg * 128 * 128);   // 1 MB packed
    float* score = (float*)carve(p, NN * 4);

    // dense count matrix (packed u8) + score zero-init
    hipMemsetAsync(cnt, 0, (size_t)BBg * 128 * 128, stream);
    hipMemsetAsync(score, 0, NN * 4, stream);
    cnt_build<<<EE / 256, 256, 0, stream>>>(srcp, dstp, (unsigned int*)cnt);

    // converts + batched weight transposes
    f32_to_bf16_vec<<<(NN * DD / 4) / 256, 256, 0, stream>>>(x, xb, NN * DD / 4);
    TP11 tps;
    for (int i = 0; i < 4; i++) tps.a[i] = {wL[i], wtcat1 + (size_t)i * DD * DD, 0};
    for (int i = 0; i < 4; i++) tps.a[4 + i] = {wL[4 + i], wtcat2 + (size_t)i * DD * DD, 0};
    tps.a[8] = {atti_w, wt8, 0};
    tps.a[9] = {atti_w, wt9, DD};
    tps.a[10] = {fc1_w, wtfc1, 0};
    transpose_batched<<<dim3(12, 12, 11), 256, 0, stream>>>(tps);

    dim3 gf(24, 64);           // fused QKVS: N=3072, M=8192
    dim3 ga(2, 2, BBg);        // attention: (dst-half, head, graph)
    // layer 1
    gemm128<<<gf, 256, 0, stream>>>(xb, wtcat1, DD, bL[0], bL[1], bL[2], bL[3],
                                    qb, kb, vt, hs, nullptr, MODE_QKVS);
    attn_fused<<<ga, 256, 0, stream>>>(qb, kb, vt, cnt, hs, hb);
    // layer 2
    gemm128<<<gf, 256, 0, stream>>>(hb, wtcat2, DD, bL[4], bL[5], bL[6], bL[7],
                                    qb, kb, vt, hs, nullptr, MODE_QKVS);
    attn_fused<<<ga, 256, 0, stream>>>(qb, kb, vt, cnt, hs, xb);   // xb = hp bf16

    // pooling: Aq = hq @ atti_w[:768]; score fused into XC epilogue (atts_b dropped:
    // uniform shift is softmax-invariant)
    gather_first<<<(BBg * DD) / 256, 256, 0, stream>>>(xb, hq);
    gemm_bf16<<<dim3(12, 1), 256, 0, stream>>>(hq, wt8, nullptr, Aq, DD, EPI_F32);
    gemm128<<<dim3(6, 64), 256, 0, stream>>>(xb, wt9, DD, atti_b, atts_w, nullptr, nullptr,
                                             score, nullptr, nullptr, nullptr, Aq, MODE_XC);
    pool_kernel<<<BBg, 192, 0, stream>>>(score, xb, pooled);

    // head: fc1 as MFMA gemm w/ tanh epilogue, then tiny fc2+log_softmax
    f32_to_bf16_vec<<<(BBg * DD / 4 + 255) / 256, 256, 0, stream>>>(pooled, pb, BBg * DD / 4);
    gemm_bf16<<<dim3(12, 1), 256, 0, stream>>>(pb, wtfc1, fc1_b, uu, DD, EPI_TANH);
    head2_kernel<<<BBg, 256, 0, stream>>>(uu, fc2_w, fc2_b, outp);
}

// Round 5
// 352.278 us; speedup vs baseline: 1.7312x; 1.0209x over previous
//
#include <hip/hip_runtime.h>

#define NN 8192
#define DD 768
#define EE 131072
#define BBg 64
#define LLn 128
#define CCh 384

typedef unsigned short u16;
typedef unsigned char u8;
typedef __attribute__((ext_vector_type(8))) short short8;
typedef __attribute__((ext_vector_type(4))) float f32x4;

__device__ __forceinline__ float b2f(u16 u) {
    union { unsigned int i; float f; } x; x.i = ((unsigned int)u) << 16; return x.f;
}
__device__ __forceinline__ u16 f2b(float f) {
    union { float f; unsigned int i; } x; x.f = f;
    unsigned int r = x.i + 0x7fffu + ((x.i >> 16) & 1u);
    return (u16)(r >> 16);
}
__device__ __forceinline__ void gload16(const void* g, void* l) {
    __builtin_amdgcn_global_load_lds((const __attribute__((address_space(1))) void*)g,
                                     (__attribute__((address_space(3))) void*)l, 16, 0, 0);
}

// ---------------- dense count matrix, packed u8 ----------------
__global__ void cnt_build(const int* __restrict__ srcp, const int* __restrict__ dstp,
                          unsigned int* __restrict__ cnt32) {
    int e = blockIdx.x * 256 + threadIdx.x;
    int d = dstp[e], s = srcp[e];
    int g = d >> 7;
    int idx = (g << 14) + ((d & 127) << 7) + (s & 127);
    atomicAdd(&cnt32[idx >> 2], 1u << ((idx & 3) * 8));
}

// ---------------- converts ----------------
__global__ void f32_to_bf16_vec(const float* __restrict__ in, u16* __restrict__ out, int n4) {
    int i = blockIdx.x * 256 + threadIdx.x;
    if (i >= n4) return;
    float4 v = ((const float4*)in)[i];
    ushort4 o; o.x = f2b(v.x); o.y = f2b(v.y); o.z = f2b(v.z); o.w = f2b(v.w);
    ((ushort4*)out)[i] = o;
}

struct TP { const float* src; u16* dst; int rowOff; };
struct TP11 { TP a[11]; };

__global__ __launch_bounds__(256) void transpose_batched(TP11 args) {
    __shared__ float tile[64][65];
    TP tp = args.a[blockIdx.z];
    int n0 = blockIdx.x * 64, k0 = blockIdx.y * 64;
    int t = threadIdx.x;
    int tc = t & 63, tr = t >> 6;
#pragma unroll
    for (int i = 0; i < 16; i++)
        tile[tr + i * 4][tc] = tp.src[(size_t)(tp.rowOff + k0 + tr + i * 4) * DD + n0 + tc];
    __syncthreads();
#pragma unroll
    for (int i = 0; i < 16; i++) {
        int row = tr + i * 4;
        tp.dst[(size_t)(n0 + row) * DD + k0 + tc] = f2b(tile[tc][row]);
    }
}

// ---------------- small GEMM (64x64 tile), for M=64 fc1 ----------------
enum { EPI_F32 = 1, EPI_TANH = 3 };

__global__ __launch_bounds__(256) void gemm_bf16(const u16* __restrict__ A,
                                                 const u16* __restrict__ Wt,
                                                 const float* __restrict__ bias,
                                                 void* __restrict__ outp, int K, int mode) {
    __shared__ u16 As[64][72];
    __shared__ u16 Bs[64][72];
    const int m0 = blockIdx.y * 64, n0 = blockIdx.x * 64;
    const int t = threadIdx.x;
    const int lane = t & 63, w = t >> 6;
    const int tr = t >> 2, tc = (t & 3) * 16;
    f32x4 acc[4] = {{0,0,0,0},{0,0,0,0},{0,0,0,0},{0,0,0,0}};
    const int fRow = lane & 15;
    const int fK = (lane >> 4) * 8;

    for (int k0 = 0; k0 < K; k0 += 64) {
        int4 a0 = *(const int4*)(A + (size_t)(m0 + tr) * K + k0 + tc);
        int4 a1 = *(const int4*)(A + (size_t)(m0 + tr) * K + k0 + tc + 8);
        int4 b0 = *(const int4*)(Wt + (size_t)(n0 + tr) * K + k0 + tc);
        int4 b1 = *(const int4*)(Wt + (size_t)(n0 + tr) * K + k0 + tc + 8);
        __syncthreads();
        *(int4*)&As[tr][tc] = a0; *(int4*)&As[tr][tc + 8] = a1;
        *(int4*)&Bs[tr][tc] = b0; *(int4*)&Bs[tr][tc + 8] = b1;
        __syncthreads();
#pragma unroll
        for (int s = 0; s < 2; s++) {
            short8 af = *(const short8*)&As[w * 16 + fRow][s * 32 + fK];
#pragma unroll
            for (int g = 0; g < 4; g++) {
                short8 bf = *(const short8*)&Bs[g * 16 + fRow][s * 32 + fK];
                acc[g] = __builtin_amdgcn_mfma_f32_16x16x32_bf16(af, bf, acc[g], 0, 0, 0);
            }
        }
    }
    const int colLocal = lane & 15;
    const int rowLocal = (lane >> 4) * 4;
#pragma unroll
    for (int g = 0; g < 4; g++) {
        int col = n0 + g * 16 + colLocal;
        float bv = bias ? bias[col] : 0.f;
#pragma unroll
        for (int i = 0; i < 4; i++) {
            int row = m0 + w * 16 + rowLocal + i;
            float v = acc[g][i] + bv;
            if (mode == EPI_TANH) v = tanhf(v);
            ((float*)outp)[(size_t)row * DD + col] = v;
        }
    }
}

// ---------------- QKVS GEMM: 256x128 tile, swizzled LDS, global_load_lds w16 ----------------
// 2x MFMA-per-staging-byte vs 128x128; __launch_bounds__(256,2) -> <=256 regs, 2 blocks/CU
__global__ __launch_bounds__(256, 2) void gemm256(const u16* __restrict__ A,
                                                  const u16* __restrict__ Wt,
                                                  const float* __restrict__ b0,
                                                  const float* __restrict__ b1,
                                                  const float* __restrict__ b2,
                                                  const float* __restrict__ b3,
                                                  u16* __restrict__ o0, u16* __restrict__ o1,
                                                  u16* __restrict__ o2, u16* __restrict__ o3) {
    __shared__ u16 As[256 * 64];   // 32 KB
    __shared__ u16 Bs[128 * 64];   // 16 KB
    const int K = DD;
    const int t = threadIdx.x;
    const int lane = t & 63, w = t >> 6;
    const int wr = w >> 1, wc = w & 1;   // wave: 128 rows x 64 cols quadrant
    const int m0 = blockIdx.y * 256, n0 = blockIdx.x * 128;
    const int fRow = lane & 15, fThr = lane >> 4;
    f32x4 acc[8][4] = {};
    const u16* Abase = A + (size_t)m0 * K;
    const u16* Bbase = Wt + (size_t)n0 * K;

    for (int k0 = 0; k0 < K; k0 += 64) {
        __syncthreads();
#pragma unroll
        for (int i = 0; i < 8; i++) {
            int c = t + 256 * i;            // 2048 A-chunks
            int row = c >> 3;
            int col = ((c & 7) ^ (row & 7)) * 8;
            gload16(Abase + (size_t)row * K + k0 + col, (char*)As + (size_t)c * 16);
        }
#pragma unroll
        for (int i = 0; i < 4; i++) {
            int c = t + 256 * i;            // 1024 B-chunks
            int row = c >> 3;
            int col = ((c & 7) ^ (row & 7)) * 8;
            gload16(Bbase + (size_t)row * K + k0 + col, (char*)Bs + (size_t)c * 16);
        }
        __syncthreads();
#pragma unroll
        for (int kk = 0; kk < 64; kk += 32) {
            const int cjW = (kk >> 3) + fThr;
            short8 af[8], bf[4];
#pragma unroll
            for (int i = 0; i < 8; i++) {
                int R = wr * 128 + i * 16 + fRow;
                af[i] = *(const short8*)&As[(R * 8 + (cjW ^ (R & 7))) * 8];
            }
#pragma unroll
            for (int g = 0; g < 4; g++) {
                int R = wc * 64 + g * 16 + fRow;
                bf[g] = *(const short8*)&Bs[(R * 8 + (cjW ^ (R & 7))) * 8];
            }
#pragma unroll
            for (int i = 0; i < 8; i++)
#pragma unroll
                for (int g = 0; g < 4; g++)
                    acc[i][g] = __builtin_amdgcn_mfma_f32_16x16x32_bf16(af[i], bf[g], acc[i][g], 0, 0, 0);
        }
    }
    // epilogue: 128-col tile never straddles a 768 boundary (768 = 6*128)
    const int chunk = (n0 + wc * 64) / DD;
    const float* bp = (chunk == 0) ? b0 : (chunk == 1) ? b1 : (chunk == 2) ? b2 : b3;
    u16* op = (chunk == 0) ? o0 : (chunk == 1) ? o1 : (chunk == 2) ? o2 : o3;
    const int cb = n0 + wc * 64 - chunk * DD;
    if (chunk == 2) {
        // V written transposed vT[c][node]: 4 consecutive rows -> ushort4
#pragma unroll
        for (int g = 0; g < 4; g++) {
            int col = cb + g * 16 + fRow;
            float bv = bp[col];
#pragma unroll
            for (int i = 0; i < 8; i++) {
                int rowb = m0 + wr * 128 + i * 16 + fThr * 4;
                ushort4 st;
                st.x = f2b(acc[i][g][0] + bv);
                st.y = f2b(acc[i][g][1] + bv);
                st.z = f2b(acc[i][g][2] + bv);
                st.w = f2b(acc[i][g][3] + bv);
                *(ushort4*)(op + (size_t)col * NN + rowb) = st;
            }
        }
    } else {
#pragma unroll
        for (int g = 0; g < 4; g++) {
            int col = cb + g * 16 + fRow;
            float bv = bp[col];
#pragma unroll
            for (int i = 0; i < 8; i++) {
                int rowb = m0 + wr * 128 + i * 16 + fThr * 4;
#pragma unroll
                for (int rr = 0; rr < 4; rr++)
                    op[(size_t)(rowb + rr) * DD + col] = f2b(acc[i][g][rr] + bv);
            }
        }
    }
}

// ---------------- XC GEMM (128x128) + inline Aq + fused score reduction ----------------
// block = (n-tile of 128 cols, graph). aq cols computed in-block (exactly the cols needed).
__global__ __launch_bounds__(256) void gemm_xc(const u16* __restrict__ A,
                                               const u16* __restrict__ Wt,
                                               const u16* __restrict__ wt8,
                                               const float* __restrict__ atti_b,
                                               const float* __restrict__ atts_w,
                                               float* __restrict__ score) {
    __shared__ u16 As[128 * 64];
    __shared__ u16 Bs[128 * 64];
    __shared__ float aq_p[2][128];
    const int K = DD;
    const int t = threadIdx.x;
    const int lane = t & 63, w = t >> 6;
    const int wr = w >> 1, wc = w & 1;
    const int n0 = blockIdx.x * 128, m0 = blockIdx.y * 128;  // graph = blockIdx.y
    const int fRow = lane & 15, fThr = lane >> 4;

    // inline Aq: aq[col] = dot(xq_row, wt8[col]), xq = first node of graph = row m0
    {
        int col = t & 127, kh = t >> 7;
        const u16* xr = A + (size_t)m0 * DD + kh * 384;
        const u16* wr8 = wt8 + (size_t)(n0 + col) * DD + kh * 384;
        float s = 0.f;
#pragma unroll 8
        for (int j = 0; j < 96; j++) {
            ushort4 a4 = *(const ushort4*)(xr + j * 4);
            ushort4 b4 = *(const ushort4*)(wr8 + j * 4);
            s += b2f(a4.x) * b2f(b4.x) + b2f(a4.y) * b2f(b4.y)
               + b2f(a4.z) * b2f(b4.z) + b2f(a4.w) * b2f(b4.w);
        }
        aq_p[kh][col] = s;
    }

    f32x4 acc[4][4] = {};
    const u16* Abase = A + (size_t)m0 * K;
    const u16* Bbase = Wt + (size_t)n0 * K;
    for (int k0 = 0; k0 < K; k0 += 64) {
        __syncthreads();
#pragma unroll
        for (int i = 0; i < 4; i++) {
            int c = t + 256 * i;
            int row = c >> 3;
            int col = ((c & 7) ^ (row & 7)) * 8;
            gload16(Abase + (size_t)row * K + k0 + col, (char*)As + (size_t)c * 16);
            gload16(Bbase + (size_t)row * K + k0 + col, (char*)Bs + (size_t)c * 16);
        }
        __syncthreads();
#pragma unroll
        for (int kk = 0; kk < 64; kk += 32) {
            const int cjW = (kk >> 3) + fThr;
            short8 af[4], bf[4];
#pragma unroll
            for (int i = 0; i < 4; i++) {
                int R = wr * 64 + i * 16 + fRow;
                af[i] = *(const short8*)&As[(R * 8 + (cjW ^ (R & 7))) * 8];
            }
#pragma unroll
            for (int g = 0; g < 4; g++) {
                int R = wc * 64 + g * 16 + fRow;
                bf[g] = *(const short8*)&Bs[(R * 8 + (cjW ^ (R & 7))) * 8];
            }
#pragma unroll
            for (int i = 0; i < 4; i++)
#pragma unroll
                for (int g = 0; g < 4; g++)
                    acc[i][g] = __builtin_amdgcn_mfma_f32_16x16x32_bf16(af[i], bf[g], acc[i][g], 0, 0, 0);
        }
    }
    // epilogue: relu(acc + atti_b + aq) . atts_w -> score[row], never materialized
    float rsum[4][4] = {};
#pragma unroll
    for (int g = 0; g < 4; g++) {
        int cl = wc * 64 + g * 16 + fRow;       // col - n0
        int col = n0 + cl;
        float bv = atti_b[col] + aq_p[0][cl] + aq_p[1][cl];
        float av = atts_w[col];
#pragma unroll
        for (int i = 0; i < 4; i++)
#pragma unroll
            for (int rr = 0; rr < 4; rr++) {
                float v = fmaxf(acc[i][g][rr] + bv, 0.f);
                rsum[i][rr] += v * av;
            }
    }
#pragma unroll
    for (int i = 0; i < 4; i++)
#pragma unroll
        for (int rr = 0; rr < 4; rr++) {
            float s = rsum[i][rr];
            s += __shfl_xor(s, 1, 16); s += __shfl_xor(s, 2, 16);
            s += __shfl_xor(s, 4, 16); s += __shfl_xor(s, 8, 16);
            if (fRow == 0)
                atomicAdd(&score[m0 + wr * 64 + i * 16 + fThr * 4 + rr], s);
        }
}

// ---------------- fused dense attention ----------------
__global__ __launch_bounds__(256) void attn_fused(const u16* __restrict__ qb,
                                                  const u16* __restrict__ kb,
                                                  const u16* __restrict__ vT,
                                                  const u8* __restrict__ cnt,
                                                  const u16* __restrict__ hs,
                                                  u16* __restrict__ out) {
    __shared__ u16 As[64][72];
    __shared__ u16 Bs[128][72];
    __shared__ u16 Pl[64][136];
    __shared__ u16 Vt[64][136];
    const int half = blockIdx.x, hd = blockIdx.y, g = blockIdx.z;
    const int t = threadIdx.x;
    const int lane = t & 63, w = t >> 6;
    const int fRow = lane & 15, fThr = lane >> 4;
    const int dstBase = g * 128 + half * 64;
    const u16* Qb = qb + (size_t)dstBase * DD + hd * CCh;
    const u16* Kb = kb + (size_t)(g * 128) * DD + hd * CCh;

    f32x4 acc[8] = {};
    const int trA = t >> 2, tcA = (t & 3) * 16;
    const int trB = t >> 1, tcB = (t & 1) * 32;
    for (int k0 = 0; k0 < CCh; k0 += 64) {
        int4 a0 = *(const int4*)(Qb + (size_t)trA * DD + k0 + tcA);
        int4 a1 = *(const int4*)(Qb + (size_t)trA * DD + k0 + tcA + 8);
        int4 b0 = *(const int4*)(Kb + (size_t)trB * DD + k0 + tcB);
        int4 b1 = *(const int4*)(Kb + (size_t)trB * DD + k0 + tcB + 8);
        int4 b2 = *(const int4*)(Kb + (size_t)trB * DD + k0 + tcB + 16);
        int4 b3 = *(const int4*)(Kb + (size_t)trB * DD + k0 + tcB + 24);
        __syncthreads();
        *(int4*)&As[trA][tcA] = a0; *(int4*)&As[trA][tcA + 8] = a1;
        *(int4*)&Bs[trB][tcB] = b0; *(int4*)&Bs[trB][tcB + 8] = b1;
        *(int4*)&Bs[trB][tcB + 16] = b2; *(int4*)&Bs[trB][tcB + 24] = b3;
        __syncthreads();
#pragma unroll
        for (int kk = 0; kk < 64; kk += 32) {
            short8 af = *(const short8*)&As[w * 16 + fRow][kk + fThr * 8];
#pragma unroll
            for (int j = 0; j < 8; j++) {
                short8 bf = *(const short8*)&Bs[j * 16 + fRow][kk + fThr * 8];
                acc[j] = __builtin_amdgcn_mfma_f32_16x16x32_bf16(af, bf, acc[j], 0, 0, 0);
            }
        }
    }

    const float scale = 0.05103103630798288f;  // 1/sqrt(384)
    const u8* cg = cnt + ((size_t)g << 14);
    const int rbase = half * 64 + w * 16 + fThr * 4;
    float pv[8][4];
#pragma unroll
    for (int i = 0; i < 4; i++) {
        float m = -3.4e38f;
#pragma unroll
        for (int j = 0; j < 8; j++) {
            float c = (float)cg[(rbase + i) * 128 + j * 16 + fRow];
            float s = acc[j][i] * scale;
            pv[j][i] = c;
            if (c > 0.f) m = fmaxf(m, s);
        }
#pragma unroll
        for (int msk = 1; msk <= 8; msk <<= 1) m = fmaxf(m, __shfl_xor(m, msk, 16));
        float sum = 0.f;
#pragma unroll
        for (int j = 0; j < 8; j++) {
            float p = (pv[j][i] > 0.f) ? pv[j][i] * __expf(acc[j][i] * scale - m) : 0.f;
            pv[j][i] = p; sum += p;
        }
#pragma unroll
        for (int msk = 1; msk <= 8; msk <<= 1) sum += __shfl_xor(sum, msk, 16);
        float inv = (sum > 0.f) ? 1.f / sum : 0.f;
#pragma unroll
        for (int j = 0; j < 8; j++)
            Pl[w * 16 + fThr * 4 + i][j * 16 + fRow] = f2b(pv[j][i] * inv);
    }

    for (int cc = 0; cc < 6; cc++) {
        __syncthreads();
#pragma unroll
        for (int ii = 0; ii < 4; ii++) {
            int q = t + 256 * ii;
            int row = q >> 4, col = (q & 15) * 8;
            *(int4*)&Vt[row][col] =
                *(const int4*)(vT + (size_t)(hd * CCh + cc * 64 + row) * NN + g * 128 + col);
        }
        __syncthreads();
        f32x4 acc2[4] = {};
#pragma unroll
        for (int kk = 0; kk < 128; kk += 32) {
            short8 af = *(const short8*)&Pl[w * 16 + fRow][kk + fThr * 8];
#pragma unroll
            for (int j = 0; j < 4; j++) {
                short8 bf = *(const short8*)&Vt[j * 16 + fRow][kk + fThr * 8];
                acc2[j] = __builtin_amdgcn_mfma_f32_16x16x32_bf16(af, bf, acc2[j], 0, 0, 0);
            }
        }
#pragma unroll
        for (int j = 0; j < 4; j++) {
            int c = hd * CCh + cc * 64 + j * 16 + fRow;
#pragma unroll
            for (int i = 0; i < 4; i++) {
                int row = dstBase + w * 16 + fThr * 4 + i;
                size_t idx = (size_t)row * DD + c;
                float r = fmaxf(acc2[j][i] + b2f(hs[idx]), 0.f);
                out[idx] = f2b(r);
            }
        }
    }
}

// ---------------- per-graph softmax + weighted pool -> bf16 ----------------
__global__ __launch_bounds__(192) void pool_kernel(const float* __restrict__ score,
                                                   const u16* __restrict__ hx,
                                                   u16* __restrict__ pb) {
    int b = blockIdx.x, t = threadIdx.x;
    __shared__ float sprob[LLn];
    if (t < 64) {
        float s0 = score[b * LLn + t];
        float s1 = score[b * LLn + 64 + t];
        float mx = fmaxf(s0, s1);
#pragma unroll
        for (int m = 1; m <= 32; m <<= 1) mx = fmaxf(mx, __shfl_xor(mx, m, 64));
        float e0 = __expf(s0 - mx), e1 = __expf(s1 - mx);
        float sum = e0 + e1;
#pragma unroll
        for (int m = 1; m <= 32; m <<= 1) sum += __shfl_xor(sum, m, 64);
        float inv = 1.f / sum;
        sprob[t] = e0 * inv; sprob[t + 64] = e1 * inv;
    }
    __syncthreads();
    int c = t * 4;
    float a0 = 0, a1 = 0, a2 = 0, a3 = 0;
    for (int l = 0; l < LLn; l++) {
        float wl = sprob[l];
        ushort4 hv = *(const ushort4*)(hx + (size_t)(b * LLn + l) * DD + c);
        a0 += wl * b2f(hv.x); a1 += wl * b2f(hv.y); a2 += wl * b2f(hv.z); a3 += wl * b2f(hv.w);
    }
    ushort4 o; o.x = f2b(a0); o.y = f2b(a1); o.z = f2b(a2); o.w = f2b(a3);
    *(ushort4*)(pb + (size_t)b * DD + c) = o;
}

// ---------------- head tail: fc2 + log_softmax ----------------
__global__ __launch_bounds__(256) void head2_kernel(const float* __restrict__ u,
                                                    const float* __restrict__ fc2w,
                                                    const float* __restrict__ fc2b,
                                                    float* __restrict__ outp) {
    int b = blockIdx.x, t = threadIdx.x;
    __shared__ float sred[4][3];
    float p0 = 0, p1 = 0, p2 = 0;
    for (int k = t; k < DD; k += 256) {
        float uv = u[(size_t)b * DD + k];
        p0 += uv * fc2w[k * 3 + 0]; p1 += uv * fc2w[k * 3 + 1]; p2 += uv * fc2w[k * 3 + 2];
    }
#pragma unroll
    for (int m = 1; m <= 32; m <<= 1) {
        p0 += __shfl_xor(p0, m, 64); p1 += __shfl_xor(p1, m, 64); p2 += __shfl_xor(p2, m, 64);
    }
    int w = t >> 6, lane = t & 63;
    if (lane == 0) { sred[w][0] = p0; sred[w][1] = p1; sred[w][2] = p2; }
    __syncthreads();
    if (t == 0) {
        float z0 = fc2b[0], z1 = fc2b[1], z2 = fc2b[2];
        for (int i = 0; i < 4; i++) { z0 += sred[i][0]; z1 += sred[i][1]; z2 += sred[i][2]; }
        float mx = fmaxf(z0, fmaxf(z1, z2));
        float lse = mx + logf(__expf(z0 - mx) + __expf(z1 - mx) + __expf(z2 - mx));
        outp[b * 3 + 0] = z0 - lse; outp[b * 3 + 1] = z1 - lse; outp[b * 3 + 2] = z2 - lse;
    }
}

// ---------------- launch ----------------
static inline char* carve(char*& p, size_t bytes) {
    char* r = p;
    p += (bytes + 255) & ~(size_t)255;
    return r;
}

extern "C" void kernel_launch(void* const* d_in, const int* in_sizes, int n_in,
                              void* d_out, int out_size, void* d_ws, size_t ws_size,
                              hipStream_t stream) {
    const float* x = (const float*)d_in[0];
    const int* ei = (const int*)d_in[1];
    const int* srcp = ei;
    const int* dstp = ei + EE;
    const float* wL[8] = {(const float*)d_in[2], (const float*)d_in[4], (const float*)d_in[6],
                          (const float*)d_in[8], (const float*)d_in[10], (const float*)d_in[12],
                          (const float*)d_in[14], (const float*)d_in[16]};
    const float* bL[8] = {(const float*)d_in[3], (const float*)d_in[5], (const float*)d_in[7],
                          (const float*)d_in[9], (const float*)d_in[11], (const float*)d_in[13],
                          (const float*)d_in[15], (const float*)d_in[17]};
    const float* atti_w = (const float*)d_in[18];
    const float* atti_b = (const float*)d_in[19];
    const float* atts_w = (const float*)d_in[20];
    const float* fc1_w = (const float*)d_in[22];
    const float* fc1_b = (const float*)d_in[23];
    const float* fc2_w = (const float*)d_in[24];
    const float* fc2_b = (const float*)d_in[25];
    float* outp = (float*)d_out;

    char* p = (char*)d_ws;
    const size_t ndb = (size_t)NN * DD * 2;
    const size_t wsz = (size_t)DD * DD * 2;
    u16* qb = (u16*)carve(p, ndb);
    u16* kb = (u16*)carve(p, ndb);
    u16* vt = (u16*)carve(p, ndb);   // V transposed [768][8192]
    u16* xb = (u16*)carve(p, ndb);   // layer1 input; reused as layer2 attn output (hp)
    u16* hb = (u16*)carve(p, ndb);   // layer1 attn output
    u16* hs = (u16*)carve(p, ndb);   // skip bf16
    u16* wtcat1 = (u16*)carve(p, wsz * 4);
    u16* wtcat2 = (u16*)carve(p, wsz * 4);
    u16* wt8 = (u16*)carve(p, wsz);
    u16* wt9 = (u16*)carve(p, wsz);
    u16* wtfc1 = (u16*)carve(p, wsz);
    u16* pb = (u16*)carve(p, (size_t)BBg * DD * 2);
    float* uu = (float*)carve(p, (size_t)BBg * DD * 4);
    u8* cnt = (u8*)carve(p, (size_t)BBg * 128 * 128);
    float* score = (float*)carve(p, NN * 4);

    hipMemsetAsync(cnt, 0, (size_t)BBg * 128 * 128, stream);
    hipMemsetAsync(score, 0, NN * 4, stream);
    cnt_build<<<EE / 256, 256, 0, stream>>>(srcp, dstp, (unsigned int*)cnt);

    f32_to_bf16_vec<<<(NN * DD / 4) / 256, 256, 0, stream>>>(x, xb, NN * DD / 4);
    TP11 tps;
    for (int i = 0; i < 4; i++) tps.a[i] = {wL[i], wtcat1 + (size_t)i * DD * DD, 0};
    for (int i = 0; i < 4; i++) tps.a[4 + i] = {wL[4 + i], wtcat2 + (size_t)i * DD * DD, 0};
    tps.a[8] = {atti_w, wt8, 0};
    tps.a[9] = {atti_w, wt9, DD};
    tps.a[10] = {fc1_w, wtfc1, 0};
    transpose_batched<<<dim3(12, 12, 11), 256, 0, stream>>>(tps);

    dim3 gf(24, 32);           // QKVS: N=3072 / 128, M=8192 / 256
    dim3 ga(2, 2, BBg);
    // layer 1
    gemm256<<<gf, 256, 0, stream>>>(xb, wtcat1, bL[0], bL[1], bL[2], bL[3], qb, kb, vt, hs);
    attn_fused<<<ga, 256, 0, stream>>>(qb, kb, vt, cnt, hs, hb);
    // layer 2
    gemm256<<<gf, 256, 0, stream>>>(hb, wtcat2, bL[4], bL[5], bL[6], bL[7], qb, kb, vt, hs);
    attn_fused<<<ga, 256, 0, stream>>>(qb, kb, vt, cnt, hs, xb);   // xb = hp bf16

    // pooling: XC with inline Aq + fused score (atts_b dropped: softmax-invariant)
    gemm_xc<<<dim3(6, 64), 256, 0, stream>>>(xb, wt9, wt8, atti_b, atts_w, score);
    pool_kernel<<<BBg, 192, 0, stream>>>(score, xb, pb);

    // head
    gemm_bf16<<<dim3(12, 1), 256, 0, stream>>>(pb, wtfc1, fc1_b, uu, DD, EPI_TANH);
    head2_kernel<<<BBg, 256, 0, stream>>>(uu, fc2_w, fc2_b, outp);
}